// Round 5
// baseline (33012.988 us; speedup 1.0000x reference)
//
#include <hip/hip_runtime.h>
#include <hip/hip_bf16.h>
#include <hip/hip_cooperative_groups.h>
#include <math.h>

namespace coopg = cooperative_groups;

#define HH 384
#define WW 384
#define HW (HH*WW)
#define BB 4
#define CC 8
#define NLAYERS 5
#define CGITERS 10
#define PI_F 3.14159265358979323846f

typedef __attribute__((ext_vector_type(8))) short short8;
typedef __attribute__((ext_vector_type(4))) float floatx4;

struct cf { float x, y; };
__device__ __forceinline__ cf cadd(cf a, cf b){ cf r; r.x=a.x+b.x; r.y=a.y+b.y; return r; }
__device__ __forceinline__ cf csub(cf a, cf b){ cf r; r.x=a.x-b.x; r.y=a.y-b.y; return r; }
__device__ __forceinline__ cf cmul(cf a, cf b){ cf r; r.x=a.x*b.x - a.y*b.y; r.y=a.x*b.y + a.y*b.x; return r; }
__device__ __forceinline__ cf shflxor(cf v, int m){ cf r; r.x = __shfl_xor(v.x, m); r.y = __shfl_xor(v.y, m); return r; }
__device__ __forceinline__ int brev7(int l){ return (int)(__brev((unsigned)l) >> 25); }
__device__ __forceinline__ int padi(int i){ return i + (i >> 3); }

__device__ __forceinline__ void radix3(cf a0, cf a1, cf a2, float s3, cf y[3]) {
  float tx = a1.x + a2.x, ty_ = a1.y + a2.y;
  float ux = a1.x - a2.x, uy = a1.y - a2.y;
  y[0].x = a0.x + tx;              y[0].y = a0.y + ty_;
  y[1].x = a0.x - 0.5f*tx - s3*uy; y[1].y = a0.y - 0.5f*ty_ + s3*ux;
  y[2].x = a0.x - 0.5f*tx + s3*uy; y[2].y = a0.y - 0.5f*ty_ - s3*ux;
}

// 384-point DFT across one 64-lane wave. SIGN=-1 fwd, +1 inverse (no 1/N scale).
// Output: uA[k1] = X[k1 + 3*rev7(l)], uB[k1] = X[k1 + 3*(rev7(l)+1)].
template<int SIGN>
__device__ __forceinline__ void fft384_wave(int l, const cf v[6], cf uA[3], cf uB[3]) {
  const float s3 = SIGN * 0.8660254037844386f;
  radix3(v[0], v[2], v[4], s3, uA);
  radix3(v[1], v[3], v[5], s3, uB);
  const float base = SIGN * (2.0f * PI_F / 384.0f);
  float sA, cA; __sincosf(base * (float)l, &sA, &cA);
  cf wA1; wA1.x = cA; wA1.y = sA; cf wA2 = cmul(wA1, wA1);
  float sB, cB; __sincosf(base * (float)(l + 64), &sB, &cB);
  cf wB1; wB1.x = cB; wB1.y = sB; cf wB2 = cmul(wB1, wB1);
  uA[1] = cmul(uA[1], wA1); uA[2] = cmul(uA[2], wA2);
  uB[1] = cmul(uB[1], wB1); uB[2] = cmul(uB[2], wB2);
  {
    float s, c; __sincosf(SIGN * (PI_F/64.0f) * (float)l, &s, &c);
    cf w; w.x = c; w.y = s;
    #pragma unroll
    for (int k1 = 0; k1 < 3; ++k1) {
      cf a = uA[k1], b = uB[k1];
      uA[k1] = cadd(a, b);
      uB[k1] = cmul(csub(a, b), w);
    }
  }
  #pragma unroll
  for (int h = 32; h >= 1; h >>= 1) {
    const int j = l & (h - 1);
    float s, c; __sincosf(SIGN * PI_F * (float)j / (float)h, &s, &c);
    cf w; w.x = c; w.y = s;
    const bool up = (l & h) != 0;
    #pragma unroll
    for (int k1 = 0; k1 < 3; ++k1) {
      cf pa = shflxor(uA[k1], h);
      cf pb = shflxor(uB[k1], h);
      cf na = up ? cmul(csub(pa, uA[k1]), w) : cadd(uA[k1], pa);
      cf nb = up ? cmul(csub(pb, uB[k1]), w) : cadd(uB[k1], pb);
      uA[k1] = na; uB[k1] = nb;
    }
  }
}

// ---------------- conv kernels (unchanged from round 4) ----------------

__global__ void repack_mid_k(const float* __restrict__ ws_mid, __hip_bfloat16* __restrict__ wrep) {
  const int idx = blockIdx.x * 256 + threadIdx.x;
  if (idx >= 7*9*64*64) return;
  const int ci = idx & 63, co = (idx >> 6) & 63, tap = (idx >> 12) % 9, i = idx / (9*4096);
  wrep[idx] = __float2bfloat16(ws_mid[(((size_t)i*64 + co)*64 + ci)*9 + tap]);
}

__global__ void __launch_bounds__(256) conv_in_k(const float* __restrict__ xin,
                                                 const float* __restrict__ w,
                                                 const float* __restrict__ bias,
                                                 __hip_bfloat16* __restrict__ out) {
  __shared__ float tile[2][340];
  const int tx = threadIdx.x & 31, ty = threadIdx.x >> 5;
  const int x0 = blockIdx.x * 32, y0 = blockIdx.y * 8, b = blockIdx.z;
  for (int e = threadIdx.x; e < 680; e += 256) {
    int ci = e / 340, rr = e % 340;
    int iy = y0 - 1 + rr / 34, ix = x0 - 1 + rr % 34;
    float v = 0.f;
    if (iy >= 0 && iy < HH && ix >= 0 && ix < WW)
      v = xin[(b*2 + ci)*HW + iy*WW + ix];
    tile[ci][rr] = v;
  }
  __syncthreads();
  float acc[64];
  #pragma unroll
  for (int co = 0; co < 64; ++co) acc[co] = bias[co];
  #pragma unroll
  for (int ci = 0; ci < 2; ++ci) {
    float v0 = tile[ci][ty*34+tx],     v1 = tile[ci][ty*34+tx+1],     v2 = tile[ci][ty*34+tx+2];
    float v3 = tile[ci][(ty+1)*34+tx], v4 = tile[ci][(ty+1)*34+tx+1], v5 = tile[ci][(ty+1)*34+tx+2];
    float v6 = tile[ci][(ty+2)*34+tx], v7 = tile[ci][(ty+2)*34+tx+1], v8 = tile[ci][(ty+2)*34+tx+2];
    #pragma unroll
    for (int co = 0; co < 64; ++co) {
      const float* wp = w + co*18 + ci*9;
      float a = acc[co];
      a = fmaf(v0, wp[0], a); a = fmaf(v1, wp[1], a); a = fmaf(v2, wp[2], a);
      a = fmaf(v3, wp[3], a); a = fmaf(v4, wp[4], a); a = fmaf(v5, wp[5], a);
      a = fmaf(v6, wp[6], a); a = fmaf(v7, wp[7], a); a = fmaf(v8, wp[8], a);
      acc[co] = a;
    }
  }
  const size_t obase = ((size_t)(b*HH + y0 + ty)*WW + (x0 + tx))*64;
  #pragma unroll
  for (int s = 0; s < 8; ++s) {
    uint4 u;
    __hip_bfloat16* hp = (__hip_bfloat16*)&u;
    #pragma unroll
    for (int j = 0; j < 8; ++j) hp[j] = __float2bfloat16(acc[s*8 + j]);
    *(uint4*)(out + obase + s*8) = u;
  }
}

__global__ void __launch_bounds__(256) conv_mid_mfma_k(
    const __hip_bfloat16* __restrict__ in,    // NHWC
    const __hip_bfloat16* __restrict__ wrep,  // [9][64][64] bf16
    const float* __restrict__ bias,
    __hip_bfloat16* __restrict__ out, int relu) {
  __shared__ __hip_bfloat16 atile[10*34*72];
  const int tid = threadIdx.x;
  const int l = tid & 63, wv = tid >> 6;
  const int x0 = blockIdx.x * 32, y0 = blockIdx.y * 8, b = blockIdx.z;

  for (int e = tid; e < 340*8; e += 256) {
    int p = e >> 3, s = e & 7;
    int iy = y0 - 1 + p / 34, ix = x0 - 1 + p % 34;
    uint4 v = make_uint4(0u, 0u, 0u, 0u);
    if (iy >= 0 && iy < HH && ix >= 0 && ix < WW)
      v = *(const uint4*)(in + ((size_t)(b*HH + iy)*WW + ix)*64 + s*8);
    *(uint4*)(&atile[p*72 + s*8]) = v;
  }

  floatx4 acc[4][4];
  #pragma unroll
  for (int mt = 0; mt < 4; ++mt)
    #pragma unroll
    for (int nt = 0; nt < 4; ++nt)
      acc[mt][nt] = (floatx4){0.f, 0.f, 0.f, 0.f};

  const int kseg = l >> 4;
  const int lr = l & 15;

  const __hip_bfloat16* wlane = wrep + lr*64 + kseg*8;
  short8 bf[4][2];
  #pragma unroll
  for (int nt = 0; nt < 4; ++nt) {
    bf[nt][0] = *(const short8*)(wlane + nt*1024);
    bf[nt][1] = *(const short8*)(wlane + nt*1024 + 32);
  }

  __syncthreads();

  #pragma unroll 1
  for (int tap = 0; tap < 9; ++tap) {
    short8 bfn[4][2];
    if (tap < 8) {
      const __hip_bfloat16* wn = wlane + (tap + 1)*4096;
      #pragma unroll
      for (int nt = 0; nt < 4; ++nt) {
        bfn[nt][0] = *(const short8*)(wn + nt*1024);
        bfn[nt][1] = *(const short8*)(wn + nt*1024 + 32);
      }
    }
    const int dy = tap / 3, dx = tap - dy*3;
    short8 af[4][2];
    #pragma unroll
    for (int mt = 0; mt < 4; ++mt) {
      const int ry = 2*wv + (mt >> 1) + dy;
      const int px = (mt & 1)*16 + lr + dx;
      const __hip_bfloat16* ap = &atile[(ry*34 + px)*72 + kseg*8];
      af[mt][0] = *(const short8*)(ap);
      af[mt][1] = *(const short8*)(ap + 32);
    }
    #pragma unroll
    for (int mt = 0; mt < 4; ++mt)
      #pragma unroll
      for (int nt = 0; nt < 4; ++nt) {
        acc[mt][nt] = __builtin_amdgcn_mfma_f32_16x16x32_bf16(af[mt][0], bf[nt][0], acc[mt][nt], 0, 0, 0);
        acc[mt][nt] = __builtin_amdgcn_mfma_f32_16x16x32_bf16(af[mt][1], bf[nt][1], acc[mt][nt], 0, 0, 0);
      }
    if (tap < 8) {
      #pragma unroll
      for (int nt = 0; nt < 4; ++nt) { bf[nt][0] = bfn[nt][0]; bf[nt][1] = bfn[nt][1]; }
    }
  }

  __syncthreads();
  __hip_bfloat16* otile = atile;        // [256 pixels][72 pad]
  #pragma unroll
  for (int mt = 0; mt < 4; ++mt) {
    const int row = 2*wv + (mt >> 1);
    #pragma unroll
    for (int nt = 0; nt < 4; ++nt) {
      const int ch = nt*16 + lr;
      const float bv = bias[ch];
      #pragma unroll
      for (int rr = 0; rr < 4; ++rr) {
        const int px = (mt & 1)*16 + kseg*4 + rr;
        float v = acc[mt][nt][rr] + bv;
        if (relu) v = fmaxf(v, 0.f);
        otile[(row*32 + px)*72 + ch] = __float2bfloat16(v);
      }
    }
  }
  __syncthreads();
  #pragma unroll
  for (int iter = 0; iter < 8; ++iter) {
    const int p = iter*32 + (tid >> 3), s = tid & 7;
    const int row = p >> 5, px = p & 31;
    uint4 v = *(const uint4*)(&otile[p*72 + s*8]);
    *(uint4*)(out + ((size_t)(b*HH + y0 + row)*WW + (x0 + px))*64 + s*8) = v;
  }
}

// conv_out (co=2) fused with CG init; rtr0 accumulates into sc[b]
__global__ void __launch_bounds__(256) conv_out_k(const __hip_bfloat16* __restrict__ in,
                                                  const float* __restrict__ w,
                                                  const float* __restrict__ bias,
                                                  const float* __restrict__ xcur,
                                                  const float* __restrict__ under,
                                                  const float* __restrict__ lam,
                                                  cf* __restrict__ r, cf* __restrict__ p,
                                                  cf* __restrict__ xc, float* __restrict__ rtr0) {
  __shared__ float wl[2*64*9];
  __shared__ float wsum[4];
  const int tx = threadIdx.x & 31, ty = threadIdx.x >> 5;
  const int x0 = blockIdx.x * 32, y0 = blockIdx.y * 8, b = blockIdx.z;
  for (int e = threadIdx.x; e < 2*64*9; e += 256) wl[e] = w[e];
  __syncthreads();
  const int y = y0 + ty, x = x0 + tx;
  float a0 = bias[0], a1 = bias[1];
  for (int tap = 0; tap < 9; ++tap) {
    const int iy = y + tap/3 - 1, ix = x + tap%3 - 1;
    if (iy < 0 || iy >= HH || ix < 0 || ix >= WW) continue;
    const __hip_bfloat16* pp = in + ((size_t)(b*HH + iy)*WW + ix)*64;
    #pragma unroll
    for (int s = 0; s < 8; ++s) {
      uint4 v = *(const uint4*)(pp + s*8);
      const __hip_bfloat16* hv = (const __hip_bfloat16*)&v;
      #pragma unroll
      for (int j = 0; j < 8; ++j) {
        const float f = __bfloat162float(hv[j]);
        a0 = fmaf(f, wl[(s*8 + j)*9 + tap], a0);
        a1 = fmaf(f, wl[(64 + s*8 + j)*9 + tap], a1);
      }
    }
  }
  const float lamv = lam[0];
  const int idx2 = y*WW + x;
  float xv0 = xcur[b*2*HW + idx2],  xv1 = xcur[b*2*HW + HW + idx2];
  float u0  = under[b*2*HW + idx2], u1  = under[b*2*HW + HW + idx2];
  float r0 = u0 + lamv * (xv0 + a0);
  float r1 = u1 + lamv * (xv1 + a1);
  const int cidx = b*HW + idx2;
  cf vv; vv.x = r0; vv.y = r1;
  r[cidx] = vv; p[cidx] = vv;
  cf zz; zz.x = 0.f; zz.y = 0.f; xc[cidx] = zz;
  float partial = r0*r0 + r1*r1;
  for (int off = 32; off; off >>= 1) partial += __shfl_down(partial, off);
  const int l = threadIdx.x & 63, wvid = threadIdx.x >> 6;
  if (l == 0) wsum[wvid] = partial;
  __syncthreads();
  if (threadIdx.x == 0) atomicAdd(&rtr0[b], wsum[0]+wsum[1]+wsum[2]+wsum[3]);
}

// ---------------- cooperative CG mega-kernel ----------------
// sc layout: rtr[it][b] = sc[it*4+b] (it=0..10), pAp[it][b] = sc[64+it*4+b].
// One launch runs all 10 CG iterations; phases separated by grid.sync().

__global__ void __launch_bounds__(256, 4) cg_solve_k(
    const cf* __restrict__ csm, const float* __restrict__ mask,
    cf* __restrict__ t, cf* __restrict__ r,
    cf* __restrict__ p0, cf* __restrict__ p1,
    cf* __restrict__ xc, cf* __restrict__ Ap0, cf* __restrict__ Ap1,
    float* __restrict__ sc, const float* __restrict__ lam,
    float* __restrict__ xout) {
  coopg::grid_group grid = coopg::this_grid();
  __shared__ cf smem[431*9];            // phase B tile; phases A/C use wave-private slices
  const int tid = threadIdx.x;
  const int l = tid & 63, wv = tid >> 6;
  const int R3 = 3 * brev7(l);
  const float lamv = lam[0];
  cf* pb[2] = { p0, p1 };

  #pragma unroll 1
  for (int it = 0; it < CGITERS; ++it) {
    cf* puse  = pb[it & 1];
    cf* pprev = pb[(it + 1) & 1];

    // ---- phase A: rows fwd FFT of csm*p (fold p-update) ----
    #pragma unroll 1
    for (int item = blockIdx.x; item < BB*CC*(HH/4); item += gridDim.x) {
      const int y = (item % 96) * 4 + wv;
      const int c = (item / 96) & 7;
      const int b = item / 768;
      const int rowoff = b*HW + y*WW;
      cf pv[6];
      if (it == 0) {
        #pragma unroll
        for (int m = 0; m < 6; ++m) pv[m] = puse[rowoff + l + 64*m];
      } else {
        const float beta = sc[it*4 + b] / sc[(it-1)*4 + b];
        #pragma unroll
        for (int m = 0; m < 6; ++m) {
          cf rv = r[rowoff + l + 64*m], po = pprev[rowoff + l + 64*m];
          pv[m].x = rv.x + beta*po.x; pv[m].y = rv.y + beta*po.y;
        }
        if (c == 0) {
          #pragma unroll
          for (int m = 0; m < 6; ++m) puse[rowoff + l + 64*m] = pv[m];
        }
      }
      const cf* crow = csm + (b*CC + c)*HW + y*WW;
      cf v[6];
      #pragma unroll
      for (int m = 0; m < 6; ++m) v[m] = cmul(crow[l + 64*m], pv[m]);
      cf uA[3], uB[3];
      fft384_wave<-1>(l, v, uA, uB);
      cf* rowbuf = smem + wv*434;       // wave-private: in-order LDS, no barrier needed
      #pragma unroll
      for (int k1 = 0; k1 < 3; ++k1) { rowbuf[padi(k1 + R3)] = uA[k1]; rowbuf[padi(k1 + R3 + 3)] = uB[k1]; }
      cf* trow = t + (b*CC + c)*HW + y*WW;
      #pragma unroll
      for (int m = 0; m < 6; ++m) trow[l + 64*m] = rowbuf[padi(l + 64*m)];
    }
    grid.sync();

    // ---- phase B: cols fwd FFT, mask, inv FFT ----
    #pragma unroll 1
    for (int item = blockIdx.x; item < BB*CC*(WW/8); item += gridDim.x) {
      const int x0 = (item % 48) * 8;
      const int c = (item / 48) & 7;
      const int b = item / 384;
      cf* base = t + (b*CC + c)*HW;
      __syncthreads();                  // previous item's readback done before overwrite
      for (int e = tid; e < 3072; e += 256) {
        int y = e >> 3, xx = e & 7;
        smem[padi(y)*9 + xx] = base[y*WW + x0 + xx];
      }
      __syncthreads();
      #pragma unroll 1
      for (int rep = 0; rep < 2; ++rep) {
        const int xx = wv*2 + rep, x = x0 + xx;
        cf v[6];
        #pragma unroll
        for (int m = 0; m < 6; ++m) v[m] = smem[padi(l + 64*m)*9 + xx];
        cf uA[3], uB[3];
        fft384_wave<-1>(l, v, uA, uB);
        const float* mrow = mask + b*HW + x;
        #pragma unroll
        for (int k1 = 0; k1 < 3; ++k1) {
          float mA = mrow[(k1 + R3)*WW], mB = mrow[(k1 + R3 + 3)*WW];
          uA[k1].x *= mA; uA[k1].y *= mA; uB[k1].x *= mB; uB[k1].y *= mB;
        }
        __syncthreads();
        #pragma unroll
        for (int k1 = 0; k1 < 3; ++k1) { smem[padi(k1 + R3)*9 + xx] = uA[k1]; smem[padi(k1 + R3 + 3)*9 + xx] = uB[k1]; }
        __syncthreads();
        #pragma unroll
        for (int m = 0; m < 6; ++m) v[m] = smem[padi(l + 64*m)*9 + xx];
        fft384_wave<1>(l, v, uA, uB);
        const float s = 1.0f / 384.0f;
        #pragma unroll
        for (int k1 = 0; k1 < 3; ++k1) {
          uA[k1].x *= s; uA[k1].y *= s; uB[k1].x *= s; uB[k1].y *= s;
          smem[padi(k1 + R3)*9 + xx] = uA[k1]; smem[padi(k1 + R3 + 3)*9 + xx] = uB[k1];
        }
        __syncthreads();
      }
      for (int e = tid; e < 3072; e += 256) {
        int y = e >> 3, xx = e & 7;
        base[y*WW + x0 + xx] = smem[padi(y)*9 + xx];
      }
    }
    grid.sync();

    // ---- phase C: rows inv FFT + conj(csm) reduce (coil-split halves) ----
    #pragma unroll 1
    for (int item = blockIdx.x; item < BB*2*(HH/4); item += gridDim.x) {
      const int y = (item % 96) * 4 + wv;
      const int half = (item / 96) & 1;
      const int b = item / 192;
      cf* rowbuf = smem + wv*434;       // wave-private
      cf acc[6] = {};
      #pragma unroll 1
      for (int ci = 0; ci < 4; ++ci) {
        const int c = half*4 + ci;
        const cf* trow = t + (b*CC + c)*HW + y*WW;
        cf v[6];
        #pragma unroll
        for (int m = 0; m < 6; ++m) v[m] = trow[l + 64*m];
        cf uA[3], uB[3];
        fft384_wave<1>(l, v, uA, uB);
        #pragma unroll
        for (int k1 = 0; k1 < 3; ++k1) { rowbuf[padi(k1 + R3)] = uA[k1]; rowbuf[padi(k1 + R3 + 3)] = uB[k1]; }
        const cf* crow = csm + (b*CC + c)*HW + y*WW;
        #pragma unroll
        for (int m = 0; m < 6; ++m) {
          cf cs = crow[l + 64*m];
          cf wz = rowbuf[padi(l + 64*m)];
          acc[m].x += cs.x*wz.x + cs.y*wz.y;
          acc[m].y += cs.x*wz.y - cs.y*wz.x;
        }
      }
      const float lv = (half == 0) ? lamv : 0.f;
      const float sc384 = 1.0f / 384.0f;
      const cf* prow = puse + b*HW + y*WW;
      cf* aprow = ((half == 0) ? Ap0 : Ap1) + b*HW + y*WW;
      float partial = 0.f;
      #pragma unroll
      for (int m = 0; m < 6; ++m) {
        cf pv = prow[l + 64*m];
        cf ap; ap.x = acc[m].x*sc384 + lv*pv.x; ap.y = acc[m].y*sc384 + lv*pv.y;
        aprow[l + 64*m] = ap;
        partial += pv.x*ap.x + pv.y*ap.y;
      }
      #pragma unroll
      for (int off = 32; off; off >>= 1) partial += __shfl_down(partial, off);
      if (l == 0) atomicAdd(&sc[64 + it*4 + b], partial);
    }
    grid.sync();

    // ---- phase U: x,r update + rtr reduce; last iter writes planar output ----
    #pragma unroll 1
    for (int item = blockIdx.x; item < (BB*HW)/256; item += gridDim.x) {
      const int idx = item*256 + tid;
      const int b = idx / HW;
      const float alpha = sc[it*4 + b] / sc[64 + it*4 + b];
      cf pv = puse[idx];
      cf a0 = Ap0[idx], a1 = Ap1[idx];
      cf apv; apv.x = a0.x + a1.x; apv.y = a0.y + a1.y;
      cf xv = xc[idx]; xv.x += alpha*pv.x; xv.y += alpha*pv.y; xc[idx] = xv;
      cf rv = r[idx]; rv.x -= alpha*apv.x; rv.y -= alpha*apv.y; r[idx] = rv;
      if (it == CGITERS - 1) {
        const int rem = idx - b*HW;
        xout[b*2*HW + rem] = xv.x;
        xout[b*2*HW + HW + rem] = xv.y;
      } else {
        float partial = rv.x*rv.x + rv.y*rv.y;
        #pragma unroll
        for (int off = 32; off; off >>= 1) partial += __shfl_down(partial, off);
        if (l == 0) atomicAdd(&sc[(it+1)*4 + b], partial);
      }
    }
    if (it < CGITERS - 1) grid.sync();
  }
}

__global__ void zero_sc_k(float* sc) { if (threadIdx.x < 128) sc[threadIdx.x] = 0.f; }

extern "C" void kernel_launch(void* const* d_in, const int* in_sizes, int n_in,
                              void* d_out, int out_size, void* d_ws, size_t ws_size,
                              hipStream_t stream) {
  (void)in_sizes; (void)n_in; (void)out_size; (void)ws_size;
  const float* under  = (const float*)d_in[0];
  const cf*    csm    = (const cf*)d_in[1];
  const float* mask   = (const float*)d_in[2];
  const float* lam    = (const float*)d_in[3];
  const float* w_in   = (const float*)d_in[4];
  const float* b_in   = (const float*)d_in[5];
  const float* ws_mid = (const float*)d_in[6];
  const float* bs_mid = (const float*)d_in[7];
  const float* w_out  = (const float*)d_in[8];
  const float* b_out  = (const float*)d_in[9];
  float* xcur = (float*)d_out;

  char* bws = (char*)d_ws;
  size_t off = 0;
  auto carve = [&](size_t bytes) { char* pp = bws + off; off += (bytes + 255) & ~(size_t)255; return (void*)pp; };
  __hip_bfloat16* actA = (__hip_bfloat16*)carve((size_t)BB*64*HW*2);
  __hip_bfloat16* actB = (__hip_bfloat16*)carve((size_t)BB*64*HW*2);
  cf* t     = (cf*)carve((size_t)BB*CC*HW*8);
  cf* r     = (cf*)carve((size_t)BB*HW*8);
  cf* pbuf0 = (cf*)carve((size_t)BB*HW*8);
  cf* pbuf1 = (cf*)carve((size_t)BB*HW*8);
  cf* xc    = (cf*)carve((size_t)BB*HW*8);
  cf* Ap0   = (cf*)carve((size_t)BB*HW*8);
  cf* Ap1   = (cf*)carve((size_t)BB*HW*8);
  float* sc = (float*)carve(256*4);
  __hip_bfloat16* wrep = (__hip_bfloat16*)carve((size_t)7*9*64*64*2);

  hipMemcpyAsync(xcur, under, (size_t)BB*2*HW*sizeof(float), hipMemcpyDeviceToDevice, stream);

  repack_mid_k<<<(7*9*64*64 + 255)/256, 256, 0, stream>>>(ws_mid, wrep);

  // cooperative grid size: clamp to co-resident capacity (deterministic host query)
  int maxb = 0;
  if (hipOccupancyMaxActiveBlocksPerMultiprocessor(&maxb, cg_solve_k, 256, 0) != hipSuccess || maxb < 1)
    maxb = 1;
  unsigned cgblocks = (unsigned)maxb * 256u;
  if (cgblocks > 3072u) cgblocks = 3072u;

  dim3 cgrid(WW/32, HH/8, BB);

  __hip_bfloat16* bufs[2] = { actA, actB };

  for (int layer = 0; layer < NLAYERS; ++layer) {
    zero_sc_k<<<1, 128, 0, stream>>>(sc);
    conv_in_k<<<cgrid, 256, 0, stream>>>(xcur, w_in, b_in, bufs[0]);
    for (int i = 0; i < 7; ++i) {
      conv_mid_mfma_k<<<cgrid, 256, 0, stream>>>(bufs[i & 1], wrep + (size_t)i*9*4096,
                                                 bs_mid + i*64, bufs[(i + 1) & 1], (i % 2 == 0) ? 1 : 0);
    }
    conv_out_k<<<cgrid, 256, 0, stream>>>(bufs[1], w_out, b_out, xcur, under, lam,
                                          r, pbuf0, xc, sc);
    void* cgargs[] = { (void*)&csm, (void*)&mask, (void*)&t, (void*)&r,
                       (void*)&pbuf0, (void*)&pbuf1, (void*)&xc, (void*)&Ap0, (void*)&Ap1,
                       (void*)&sc, (void*)&lam, (void*)&xcur };
    hipLaunchCooperativeKernel(cg_solve_k, dim3(cgblocks), dim3(256), cgargs, 0, stream);
  }
}

// Round 6
// 13710.706 us; speedup vs baseline: 2.4078x; 2.4078x over previous
//
#include <hip/hip_runtime.h>
#include <hip/hip_bf16.h>
#include <math.h>

#define HH 384
#define WW 384
#define HW (HH*WW)
#define BB 4
#define CC 8
#define NLAYERS 5
#define CGITERS 10
#define PI_F 3.14159265358979323846f

typedef __attribute__((ext_vector_type(8))) short short8;
typedef __attribute__((ext_vector_type(4))) float floatx4;

struct cf { float x, y; };
__device__ __forceinline__ cf cadd(cf a, cf b){ cf r; r.x=a.x+b.x; r.y=a.y+b.y; return r; }
__device__ __forceinline__ cf csub(cf a, cf b){ cf r; r.x=a.x-b.x; r.y=a.y-b.y; return r; }
__device__ __forceinline__ cf cmul(cf a, cf b){ cf r; r.x=a.x*b.x - a.y*b.y; r.y=a.x*b.y + a.y*b.x; return r; }
__device__ __forceinline__ cf shflxor(cf v, int m){ cf r; r.x = __shfl_xor(v.x, m); r.y = __shfl_xor(v.y, m); return r; }
__device__ __forceinline__ int brev7(int l){ return (int)(__brev((unsigned)l) >> 25); }
__device__ __forceinline__ int padi(int i){ return i + (i >> 3); }

__device__ __forceinline__ void radix3(cf a0, cf a1, cf a2, float s3, cf y[3]) {
  float tx = a1.x + a2.x, ty_ = a1.y + a2.y;
  float ux = a1.x - a2.x, uy = a1.y - a2.y;
  y[0].x = a0.x + tx;              y[0].y = a0.y + ty_;
  y[1].x = a0.x - 0.5f*tx - s3*uy; y[1].y = a0.y - 0.5f*ty_ + s3*ux;
  y[2].x = a0.x - 0.5f*tx + s3*uy; y[2].y = a0.y - 0.5f*ty_ - s3*ux;
}

// 384-point DFT across one 64-lane wave. SIGN=-1 fwd, +1 inverse (no 1/N scale).
// Output: uA[k1] = X[k1 + 3*rev7(l)], uB[k1] = X[k1 + 3*(rev7(l)+1)].
template<int SIGN>
__device__ __forceinline__ void fft384_wave(int l, const cf v[6], cf uA[3], cf uB[3]) {
  const float s3 = SIGN * 0.8660254037844386f;
  radix3(v[0], v[2], v[4], s3, uA);
  radix3(v[1], v[3], v[5], s3, uB);
  const float base = SIGN * (2.0f * PI_F / 384.0f);
  float sA, cA; __sincosf(base * (float)l, &sA, &cA);
  cf wA1; wA1.x = cA; wA1.y = sA; cf wA2 = cmul(wA1, wA1);
  float sB, cB; __sincosf(base * (float)(l + 64), &sB, &cB);
  cf wB1; wB1.x = cB; wB1.y = sB; cf wB2 = cmul(wB1, wB1);
  uA[1] = cmul(uA[1], wA1); uA[2] = cmul(uA[2], wA2);
  uB[1] = cmul(uB[1], wB1); uB[2] = cmul(uB[2], wB2);
  {
    float s, c; __sincosf(SIGN * (PI_F/64.0f) * (float)l, &s, &c);
    cf w; w.x = c; w.y = s;
    #pragma unroll
    for (int k1 = 0; k1 < 3; ++k1) {
      cf a = uA[k1], b = uB[k1];
      uA[k1] = cadd(a, b);
      uB[k1] = cmul(csub(a, b), w);
    }
  }
  #pragma unroll
  for (int h = 32; h >= 1; h >>= 1) {
    const int j = l & (h - 1);
    float s, c; __sincosf(SIGN * PI_F * (float)j / (float)h, &s, &c);
    cf w; w.x = c; w.y = s;
    const bool up = (l & h) != 0;
    #pragma unroll
    for (int k1 = 0; k1 < 3; ++k1) {
      cf pa = shflxor(uA[k1], h);
      cf pb = shflxor(uB[k1], h);
      cf na = up ? cmul(csub(pa, uA[k1]), w) : cadd(uA[k1], pa);
      cf nb = up ? cmul(csub(pb, uB[k1]), w) : cadd(uB[k1], pb);
      uA[k1] = na; uB[k1] = nb;
    }
  }
}

// ---------------- conv kernels ----------------
// Activations in NHWC bf16: act[b][y][x][c], c=64 contiguous.

__global__ void repack_mid_k(const float* __restrict__ ws_mid, __hip_bfloat16* __restrict__ wrep) {
  const int idx = blockIdx.x * 256 + threadIdx.x;
  if (idx >= 7*9*64*64) return;
  const int ci = idx & 63, co = (idx >> 6) & 63, tap = (idx >> 12) % 9, i = idx / (9*4096);
  wrep[idx] = __float2bfloat16(ws_mid[(((size_t)i*64 + co)*64 + ci)*9 + tap]);
}

__global__ void __launch_bounds__(256) conv_in_k(const float* __restrict__ xin,
                                                 const float* __restrict__ w,
                                                 const float* __restrict__ bias,
                                                 __hip_bfloat16* __restrict__ out) {
  __shared__ float tile[2][340];
  const int tx = threadIdx.x & 31, ty = threadIdx.x >> 5;
  const int x0 = blockIdx.x * 32, y0 = blockIdx.y * 8, b = blockIdx.z;
  for (int e = threadIdx.x; e < 680; e += 256) {
    int ci = e / 340, rr = e % 340;
    int iy = y0 - 1 + rr / 34, ix = x0 - 1 + rr % 34;
    float v = 0.f;
    if (iy >= 0 && iy < HH && ix >= 0 && ix < WW)
      v = xin[(b*2 + ci)*HW + iy*WW + ix];
    tile[ci][rr] = v;
  }
  __syncthreads();
  float acc[64];
  #pragma unroll
  for (int co = 0; co < 64; ++co) acc[co] = bias[co];
  #pragma unroll
  for (int ci = 0; ci < 2; ++ci) {
    float v0 = tile[ci][ty*34+tx],     v1 = tile[ci][ty*34+tx+1],     v2 = tile[ci][ty*34+tx+2];
    float v3 = tile[ci][(ty+1)*34+tx], v4 = tile[ci][(ty+1)*34+tx+1], v5 = tile[ci][(ty+1)*34+tx+2];
    float v6 = tile[ci][(ty+2)*34+tx], v7 = tile[ci][(ty+2)*34+tx+1], v8 = tile[ci][(ty+2)*34+tx+2];
    #pragma unroll
    for (int co = 0; co < 64; ++co) {
      const float* wp = w + co*18 + ci*9;
      float a = acc[co];
      a = fmaf(v0, wp[0], a); a = fmaf(v1, wp[1], a); a = fmaf(v2, wp[2], a);
      a = fmaf(v3, wp[3], a); a = fmaf(v4, wp[4], a); a = fmaf(v5, wp[5], a);
      a = fmaf(v6, wp[6], a); a = fmaf(v7, wp[7], a); a = fmaf(v8, wp[8], a);
      acc[co] = a;
    }
  }
  const size_t obase = ((size_t)(b*HH + y0 + ty)*WW + (x0 + tx))*64;
  #pragma unroll
  for (int s = 0; s < 8; ++s) {
    uint4 u;
    __hip_bfloat16* hp = (__hip_bfloat16*)&u;
    #pragma unroll
    for (int j = 0; j < 8; ++j) hp[j] = __float2bfloat16(acc[s*8 + j]);
    *(uint4*)(out + obase + s*8) = u;
  }
}

// MFMA implicit-GEMM mid conv, re-tiled for occupancy: BM=128 (32x4), per-wave
// 2x4 16x16 tiles (32 acc VGPRs), no register double-buffer. ~120 VGPR, 29KB LDS
// -> 4-5 blocks/CU (was 1-2 with the 256-pixel/64-acc tile).
__global__ void __launch_bounds__(256) conv_mid_mfma_k(
    const __hip_bfloat16* __restrict__ in,    // NHWC
    const __hip_bfloat16* __restrict__ wrep,  // [9][64][64] bf16
    const float* __restrict__ bias,
    __hip_bfloat16* __restrict__ out, int relu) {
  __shared__ __hip_bfloat16 atile[6*34*72];   // 29376 B, ch padded 64->72
  const int tid = threadIdx.x;
  const int l = tid & 63, wv = tid >> 6;
  const int x0 = blockIdx.x * 32, y0 = blockIdx.y * 4, b = blockIdx.z;

  for (int e = tid; e < 204*8; e += 256) {
    int p = e >> 3, s = e & 7;
    int iy = y0 - 1 + p / 34, ix = x0 - 1 + p % 34;
    uint4 v = make_uint4(0u, 0u, 0u, 0u);
    if (iy >= 0 && iy < HH && ix >= 0 && ix < WW)
      v = *(const uint4*)(in + ((size_t)(b*HH + iy)*WW + ix)*64 + s*8);
    *(uint4*)(&atile[p*72 + s*8]) = v;
  }

  floatx4 acc[2][4];
  #pragma unroll
  for (int mt = 0; mt < 2; ++mt)
    #pragma unroll
    for (int nt = 0; nt < 4; ++nt)
      acc[mt][nt] = (floatx4){0.f, 0.f, 0.f, 0.f};

  const int kseg = l >> 4;
  const int lr = l & 15;

  __syncthreads();

  #pragma unroll 1
  for (int tap = 0; tap < 9; ++tap) {
    const int dy = tap / 3, dx = tap - dy*3;
    const __hip_bfloat16* wt = wrep + tap*4096 + lr*64 + kseg*8;
    short8 bf[4][2];
    #pragma unroll
    for (int nt = 0; nt < 4; ++nt) {
      bf[nt][0] = *(const short8*)(wt + nt*1024);
      bf[nt][1] = *(const short8*)(wt + nt*1024 + 32);
    }
    short8 af[2][2];
    #pragma unroll
    for (int mt = 0; mt < 2; ++mt) {
      const int py = wv + dy;
      const int px = mt*16 + lr + dx;
      const __hip_bfloat16* ap = &atile[(py*34 + px)*72 + kseg*8];
      af[mt][0] = *(const short8*)(ap);
      af[mt][1] = *(const short8*)(ap + 32);
    }
    #pragma unroll
    for (int mt = 0; mt < 2; ++mt)
      #pragma unroll
      for (int nt = 0; nt < 4; ++nt) {
        acc[mt][nt] = __builtin_amdgcn_mfma_f32_16x16x32_bf16(af[mt][0], bf[nt][0], acc[mt][nt], 0, 0, 0);
        acc[mt][nt] = __builtin_amdgcn_mfma_f32_16x16x32_bf16(af[mt][1], bf[nt][1], acc[mt][nt], 0, 0, 0);
      }
  }

  // LDS-transpose epilogue -> coalesced 16B stores
  __syncthreads();
  __hip_bfloat16* otile = atile;        // [128 pixels][72 pad] = 18432 B
  #pragma unroll
  for (int mt = 0; mt < 2; ++mt) {
    #pragma unroll
    for (int nt = 0; nt < 4; ++nt) {
      const int ch = nt*16 + lr;
      const float bv = bias[ch];
      #pragma unroll
      for (int rr = 0; rr < 4; ++rr) {
        const int px = mt*16 + kseg*4 + rr;
        float v = acc[mt][nt][rr] + bv;
        if (relu) v = fmaxf(v, 0.f);
        otile[(wv*32 + px)*72 + ch] = __float2bfloat16(v);
      }
    }
  }
  __syncthreads();
  #pragma unroll
  for (int iter = 0; iter < 4; ++iter) {
    const int e = iter*256 + tid;
    const int p = e >> 3, s = e & 7;       // p: 0..127
    const int row = p >> 5, px = p & 31;
    uint4 v = *(const uint4*)(&otile[p*72 + s*8]);
    *(uint4*)(out + ((size_t)(b*HH + y0 + row)*WW + (x0 + px))*64 + s*8) = v;
  }
}

// conv_out (co=2) fused with CG init; rtr0 accumulates into scL[b]
__global__ void __launch_bounds__(256) conv_out_k(const __hip_bfloat16* __restrict__ in,
                                                  const float* __restrict__ w,
                                                  const float* __restrict__ bias,
                                                  const float* __restrict__ xcur,
                                                  const float* __restrict__ under,
                                                  const float* __restrict__ lam,
                                                  cf* __restrict__ r, cf* __restrict__ p,
                                                  cf* __restrict__ xc, float* __restrict__ scL) {
  __shared__ float wl[2*64*9];
  __shared__ float wsum[4];
  const int tx = threadIdx.x & 31, ty = threadIdx.x >> 5;
  const int x0 = blockIdx.x * 32, y0 = blockIdx.y * 8, b = blockIdx.z;
  for (int e = threadIdx.x; e < 2*64*9; e += 256) wl[e] = w[e];
  __syncthreads();
  const int y = y0 + ty, x = x0 + tx;
  float a0 = bias[0], a1 = bias[1];
  for (int tap = 0; tap < 9; ++tap) {
    const int iy = y + tap/3 - 1, ix = x + tap%3 - 1;
    if (iy < 0 || iy >= HH || ix < 0 || ix >= WW) continue;
    const __hip_bfloat16* pp = in + ((size_t)(b*HH + iy)*WW + ix)*64;
    #pragma unroll
    for (int s = 0; s < 8; ++s) {
      uint4 v = *(const uint4*)(pp + s*8);
      const __hip_bfloat16* hv = (const __hip_bfloat16*)&v;
      #pragma unroll
      for (int j = 0; j < 8; ++j) {
        const float f = __bfloat162float(hv[j]);
        a0 = fmaf(f, wl[(s*8 + j)*9 + tap], a0);
        a1 = fmaf(f, wl[(64 + s*8 + j)*9 + tap], a1);
      }
    }
  }
  const float lamv = lam[0];
  const int idx2 = y*WW + x;
  float xv0 = xcur[b*2*HW + idx2],  xv1 = xcur[b*2*HW + HW + idx2];
  float u0  = under[b*2*HW + idx2], u1  = under[b*2*HW + HW + idx2];
  float r0 = u0 + lamv * (xv0 + a0);
  float r1 = u1 + lamv * (xv1 + a1);
  const int cidx = b*HW + idx2;
  cf vv; vv.x = r0; vv.y = r1;
  r[cidx] = vv; p[cidx] = vv;
  cf zz; zz.x = 0.f; zz.y = 0.f; xc[cidx] = zz;
  float partial = r0*r0 + r1*r1;
  for (int off = 32; off; off >>= 1) partial += __shfl_down(partial, off);
  const int l = threadIdx.x & 63, wvid = threadIdx.x >> 6;
  if (l == 0) wsum[wvid] = partial;
  __syncthreads();
  if (threadIdx.x == 0) atomicAdd(&scL[b], wsum[0]+wsum[1]+wsum[2]+wsum[3]);
}

// ---------------- CG / FFT kernels ----------------
// Per-layer scalar slice scL (128 floats): rtr[it][b]=scL[it*4+b],
// pAp[it][b]=scL[40+it*4+b], ApAp[it][b]=scL[80+it*4+b]. Zeroed once per call.
// 3 dispatches/iter: A (updates x,r,p via recurrence + row FFT), B (cols), C
// (row IFFT + reduce pAp & ApAp). rtr recurrence: rtr_new = a^2*ApAp - rtr.

__global__ void __launch_bounds__(256) pass_a_k(const cf* __restrict__ rold, cf* __restrict__ rnew,
                                                const cf* __restrict__ pold, cf* __restrict__ pnew,
                                                cf* __restrict__ xc, const cf* __restrict__ Ap,
                                                const cf* __restrict__ csm, cf* __restrict__ t,
                                                float* __restrict__ scL, int it) {
  __shared__ cf rowbuf[4][434];
  const int l = threadIdx.x & 63, wv = threadIdx.x >> 6;
  const int y = blockIdx.x * 4 + wv;
  const int c = blockIdx.y, b = blockIdx.z;
  const int rowoff = b*HW + y*WW;
  cf pv[6];
  if (it == 0) {
    #pragma unroll
    for (int m = 0; m < 6; ++m) pv[m] = pold[rowoff + l + 64*m];
  } else {
    const float rtrp  = scL[(it-1)*4 + b];
    const float pApp  = scL[40 + (it-1)*4 + b];
    const float ApApp = scL[80 + (it-1)*4 + b];
    const float alpha = rtrp / pApp;
    const float rtrn  = alpha*alpha*ApApp - rtrp;
    const float beta  = rtrn / rtrp;
    if (blockIdx.x == 0 && c == 0 && threadIdx.x == 0) scL[it*4 + b] = rtrn;
    #pragma unroll
    for (int m = 0; m < 6; ++m) {
      const int idx = rowoff + l + 64*m;
      cf rv = rold[idx];
      cf av = Ap[idx];
      rv.x -= alpha*av.x; rv.y -= alpha*av.y;
      cf po = pold[idx];
      pv[m].x = rv.x + beta*po.x; pv[m].y = rv.y + beta*po.y;
      if (c == 0) {
        rnew[idx] = rv;
        pnew[idx] = pv[m];
        cf xv = xc[idx]; xv.x += alpha*po.x; xv.y += alpha*po.y; xc[idx] = xv;
      }
    }
  }
  const cf* crow = csm + (b*CC + c)*HW + y*WW;
  cf v[6];
  #pragma unroll
  for (int m = 0; m < 6; ++m) v[m] = cmul(crow[l + 64*m], pv[m]);
  cf uA[3], uB[3];
  fft384_wave<-1>(l, v, uA, uB);
  const int R3 = 3 * brev7(l);
  cf* rb = rowbuf[wv];                  // wave-private: no barrier needed
  #pragma unroll
  for (int k1 = 0; k1 < 3; ++k1) { rb[padi(k1 + R3)] = uA[k1]; rb[padi(k1 + R3 + 3)] = uB[k1]; }
  cf* trow = t + (b*CC + c)*HW + y*WW;
  #pragma unroll
  for (int m = 0; m < 6; ++m) trow[l + 64*m] = rb[padi(l + 64*m)];
}

__global__ void __launch_bounds__(256) pass_b_k(cf* __restrict__ t, const float* __restrict__ mask) {
  __shared__ cf tile[431*9];
  const int b = blockIdx.z, c = blockIdx.y, x0 = blockIdx.x * 8;
  cf* base = t + (b*CC + c)*HW;
  for (int e = threadIdx.x; e < 3072; e += 256) {
    int y = e >> 3, xx = e & 7;
    tile[padi(y)*9 + xx] = base[y*WW + x0 + xx];
  }
  __syncthreads();
  const int l = threadIdx.x & 63, wv = threadIdx.x >> 6;
  const int R3 = 3 * brev7(l);
  for (int rep = 0; rep < 2; ++rep) {
    const int xx = wv*2 + rep, x = x0 + xx;
    cf v[6];
    #pragma unroll
    for (int m = 0; m < 6; ++m) v[m] = tile[padi(l + 64*m)*9 + xx];
    cf uA[3], uB[3];
    fft384_wave<-1>(l, v, uA, uB);
    const float* mrow = mask + b*HW + x;
    #pragma unroll
    for (int k1 = 0; k1 < 3; ++k1) {
      float mA = mrow[(k1 + R3)*WW], mB = mrow[(k1 + R3 + 3)*WW];
      uA[k1].x *= mA; uA[k1].y *= mA; uB[k1].x *= mB; uB[k1].y *= mB;
    }
    __syncthreads();
    #pragma unroll
    for (int k1 = 0; k1 < 3; ++k1) { tile[padi(k1 + R3)*9 + xx] = uA[k1]; tile[padi(k1 + R3 + 3)*9 + xx] = uB[k1]; }
    __syncthreads();
    #pragma unroll
    for (int m = 0; m < 6; ++m) v[m] = tile[padi(l + 64*m)*9 + xx];
    fft384_wave<1>(l, v, uA, uB);
    const float s = 1.0f / 384.0f;
    #pragma unroll
    for (int k1 = 0; k1 < 3; ++k1) {
      uA[k1].x *= s; uA[k1].y *= s; uB[k1].x *= s; uB[k1].y *= s;
      tile[padi(k1 + R3)*9 + xx] = uA[k1]; tile[padi(k1 + R3 + 3)*9 + xx] = uB[k1];
    }
    __syncthreads();
  }
  for (int e = threadIdx.x; e < 3072; e += 256) {
    int y = e >> 3, xx = e & 7;
    base[y*WW + x0 + xx] = tile[padi(y)*9 + xx];
  }
}

// rows: Ap = (1/384) sum_c conj(csm)*rowIFFT(t) + lam*p; reduce pAp AND ApAp.
__global__ void __launch_bounds__(256) pass_c_k(const cf* __restrict__ t, const cf* __restrict__ csm,
                                                const cf* __restrict__ p, cf* __restrict__ Ap,
                                                const float* __restrict__ lam,
                                                float* __restrict__ scL, int it) {
  __shared__ cf rowbuf[4][434];
  __shared__ float wsum[4][2];
  const int l = threadIdx.x & 63, wv = threadIdx.x >> 6;
  const int y = blockIdx.x * 4 + wv, b = blockIdx.y;
  const int R3 = 3 * brev7(l);
  cf* rb = rowbuf[wv];                  // wave-private
  cf acc[6] = {};
  #pragma unroll 1
  for (int c = 0; c < CC; ++c) {
    const cf* trow = t + (b*CC + c)*HW + y*WW;
    cf v[6];
    #pragma unroll
    for (int m = 0; m < 6; ++m) v[m] = trow[l + 64*m];
    cf uA[3], uB[3];
    fft384_wave<1>(l, v, uA, uB);
    #pragma unroll
    for (int k1 = 0; k1 < 3; ++k1) { rb[padi(k1 + R3)] = uA[k1]; rb[padi(k1 + R3 + 3)] = uB[k1]; }
    const cf* crow = csm + (b*CC + c)*HW + y*WW;
    #pragma unroll
    for (int m = 0; m < 6; ++m) {
      cf cs = crow[l + 64*m];
      cf wz = rb[padi(l + 64*m)];
      acc[m].x += cs.x*wz.x + cs.y*wz.y;
      acc[m].y += cs.x*wz.y - cs.y*wz.x;
    }
  }
  const float lamv = lam[0];
  const float sc384 = 1.0f / 384.0f;
  const cf* prow = p + b*HW + y*WW;
  cf* aprow = Ap + b*HW + y*WW;
  float partial = 0.f, partial2 = 0.f;
  #pragma unroll
  for (int m = 0; m < 6; ++m) {
    cf pv = prow[l + 64*m];
    cf ap; ap.x = acc[m].x*sc384 + lamv*pv.x; ap.y = acc[m].y*sc384 + lamv*pv.y;
    aprow[l + 64*m] = ap;
    partial  += pv.x*ap.x + pv.y*ap.y;
    partial2 += ap.x*ap.x + ap.y*ap.y;
  }
  for (int off = 32; off; off >>= 1) {
    partial  += __shfl_down(partial, off);
    partial2 += __shfl_down(partial2, off);
  }
  if (l == 0) { wsum[wv][0] = partial; wsum[wv][1] = partial2; }
  __syncthreads();
  if (threadIdx.x == 0) {
    atomicAdd(&scL[40 + it*4 + b], wsum[0][0]+wsum[1][0]+wsum[2][0]+wsum[3][0]);
    atomicAdd(&scL[80 + it*4 + b], wsum[0][1]+wsum[1][1]+wsum[2][1]+wsum[3][1]);
  }
}

// final x = xc + alpha9 * p9, written planar to output
__global__ void __launch_bounds__(256) final_x_k(const cf* __restrict__ xc, const cf* __restrict__ p9,
                                                 const float* __restrict__ scL, float* __restrict__ out) {
  const int idx = blockIdx.x * 256 + threadIdx.x;
  const int b = idx / HW;
  const int rem = idx - b*HW;
  const float alpha = scL[(CGITERS-1)*4 + b] / scL[40 + (CGITERS-1)*4 + b];
  cf xv = xc[idx], pv = p9[idx];
  xv.x += alpha*pv.x; xv.y += alpha*pv.y;
  out[b*2*HW + rem] = xv.x;
  out[b*2*HW + HW + rem] = xv.y;
}

__global__ void zero_sc_k(float* sc) {
  for (int i = threadIdx.x; i < NLAYERS*128; i += 256) sc[i] = 0.f;
}

extern "C" void kernel_launch(void* const* d_in, const int* in_sizes, int n_in,
                              void* d_out, int out_size, void* d_ws, size_t ws_size,
                              hipStream_t stream) {
  (void)in_sizes; (void)n_in; (void)out_size; (void)ws_size;
  const float* under  = (const float*)d_in[0];
  const cf*    csm    = (const cf*)d_in[1];
  const float* mask   = (const float*)d_in[2];
  const float* lam    = (const float*)d_in[3];
  const float* w_in   = (const float*)d_in[4];
  const float* b_in   = (const float*)d_in[5];
  const float* ws_mid = (const float*)d_in[6];
  const float* bs_mid = (const float*)d_in[7];
  const float* w_out  = (const float*)d_in[8];
  const float* b_out  = (const float*)d_in[9];
  float* xcur = (float*)d_out;

  char* bws = (char*)d_ws;
  size_t off = 0;
  auto carve = [&](size_t bytes) { char* pp = bws + off; off += (bytes + 255) & ~(size_t)255; return (void*)pp; };
  __hip_bfloat16* actA = (__hip_bfloat16*)carve((size_t)BB*64*HW*2);
  __hip_bfloat16* actB = (__hip_bfloat16*)carve((size_t)BB*64*HW*2);
  cf* t     = (cf*)carve((size_t)BB*CC*HW*8);
  cf* rbuf0 = (cf*)carve((size_t)BB*HW*8);
  cf* rbuf1 = (cf*)carve((size_t)BB*HW*8);
  cf* pbuf0 = (cf*)carve((size_t)BB*HW*8);
  cf* pbuf1 = (cf*)carve((size_t)BB*HW*8);
  cf* xc    = (cf*)carve((size_t)BB*HW*8);
  cf* Ap    = (cf*)carve((size_t)BB*HW*8);
  float* sc = (float*)carve(4096);
  __hip_bfloat16* wrep = (__hip_bfloat16*)carve((size_t)7*9*64*64*2);

  hipMemcpyAsync(xcur, under, (size_t)BB*2*HW*sizeof(float), hipMemcpyDeviceToDevice, stream);

  zero_sc_k<<<1, 256, 0, stream>>>(sc);
  repack_mid_k<<<(7*9*64*64 + 255)/256, 256, 0, stream>>>(ws_mid, wrep);

  dim3 cgrid(WW/32, HH/8, BB);       // conv_in / conv_out (32x8 tiles)
  dim3 mgrid(WW/32, HH/4, BB);       // conv_mid (32x4 tiles)
  dim3 agrid(HH/4, CC, BB);
  dim3 bgrid(WW/8, CC, BB);
  dim3 c2grid(HH/4, BB);
  const int egrid = BB*HW/256;

  __hip_bfloat16* bufs[2] = { actA, actB };
  cf* rb[2] = { rbuf0, rbuf1 };
  cf* pb[2] = { pbuf0, pbuf1 };

  for (int layer = 0; layer < NLAYERS; ++layer) {
    float* scL = sc + layer*128;
    conv_in_k<<<cgrid, 256, 0, stream>>>(xcur, w_in, b_in, bufs[0]);
    for (int i = 0; i < 7; ++i) {
      conv_mid_mfma_k<<<mgrid, 256, 0, stream>>>(bufs[i & 1], wrep + (size_t)i*9*4096,
                                                 bs_mid + i*64, bufs[(i + 1) & 1], (i % 2 == 0) ? 1 : 0);
    }
    conv_out_k<<<cgrid, 256, 0, stream>>>(bufs[1], w_out, b_out, xcur, under, lam,
                                          rbuf0, pbuf0, xc, scL);
    for (int it = 0; it < CGITERS; ++it) {
      cf* rold = rb[(it + 1) & 1];
      cf* rnew = rb[it & 1];
      cf* pold = pb[(it + 1) & 1];
      cf* pnew = pb[it & 1];
      // note: it==0 -> rold/pold indices give rb[1]/pb[1]; kernel only reads pold
      // when it==0, so pass the real initial buffers explicitly:
      if (it == 0) { rold = rbuf0; pold = pbuf0; rnew = rbuf0; pnew = pbuf0; }
      pass_a_k<<<agrid, 256, 0, stream>>>(rold, rnew, pold, pnew, xc, Ap, csm, t, scL, it);
      pass_b_k<<<bgrid, 256, 0, stream>>>(t, mask);
      pass_c_k<<<c2grid, 256, 0, stream>>>(t, csm, pnew, Ap, lam, scL, it);
    }
    final_x_k<<<egrid, 256, 0, stream>>>(xc, pb[(CGITERS - 1) & 1], scL, xcur);
  }
}

// Round 7
// 11047.631 us; speedup vs baseline: 2.9882x; 1.2411x over previous
//
#include <hip/hip_runtime.h>
#include <hip/hip_bf16.h>
#include <math.h>

#define HH 384
#define WW 384
#define HW (HH*WW)
#define BB 4
#define CC 8
#define NLAYERS 5
#define CGITERS 10
#define PI_F 3.14159265358979323846f

typedef __attribute__((ext_vector_type(8))) short short8;
typedef __attribute__((ext_vector_type(4))) float floatx4;

struct cf { float x, y; };
__device__ __forceinline__ cf cadd(cf a, cf b){ cf r; r.x=a.x+b.x; r.y=a.y+b.y; return r; }
__device__ __forceinline__ cf csub(cf a, cf b){ cf r; r.x=a.x-b.x; r.y=a.y-b.y; return r; }
__device__ __forceinline__ cf cmul(cf a, cf b){ cf r; r.x=a.x*b.x - a.y*b.y; r.y=a.x*b.y + a.y*b.x; return r; }
__device__ __forceinline__ cf shflxor(cf v, int m){ cf r; r.x = __shfl_xor(v.x, m); r.y = __shfl_xor(v.y, m); return r; }
__device__ __forceinline__ int brev7(int l){ return (int)(__brev((unsigned)l) >> 25); }
__device__ __forceinline__ int padi(int i){ return i + (i >> 3); }

__device__ __forceinline__ void radix3(cf a0, cf a1, cf a2, float s3, cf y[3]) {
  float tx = a1.x + a2.x, ty_ = a1.y + a2.y;
  float ux = a1.x - a2.x, uy = a1.y - a2.y;
  y[0].x = a0.x + tx;              y[0].y = a0.y + ty_;
  y[1].x = a0.x - 0.5f*tx - s3*uy; y[1].y = a0.y - 0.5f*ty_ + s3*ux;
  y[2].x = a0.x - 0.5f*tx + s3*uy; y[2].y = a0.y - 0.5f*ty_ - s3*ux;
}

// 384-point DFT across one 64-lane wave. SIGN=-1 fwd, +1 inverse (no 1/N scale).
// Output: uA[k1] = X[k1 + 3*rev7(l)], uB[k1] = X[k1 + 3*(rev7(l)+1)].
template<int SIGN>
__device__ __forceinline__ void fft384_wave(int l, const cf v[6], cf uA[3], cf uB[3]) {
  const float s3 = SIGN * 0.8660254037844386f;
  radix3(v[0], v[2], v[4], s3, uA);
  radix3(v[1], v[3], v[5], s3, uB);
  const float base = SIGN * (2.0f * PI_F / 384.0f);
  float sA, cA; __sincosf(base * (float)l, &sA, &cA);
  cf wA1; wA1.x = cA; wA1.y = sA; cf wA2 = cmul(wA1, wA1);
  float sB, cB; __sincosf(base * (float)(l + 64), &sB, &cB);
  cf wB1; wB1.x = cB; wB1.y = sB; cf wB2 = cmul(wB1, wB1);
  uA[1] = cmul(uA[1], wA1); uA[2] = cmul(uA[2], wA2);
  uB[1] = cmul(uB[1], wB1); uB[2] = cmul(uB[2], wB2);
  {
    float s, c; __sincosf(SIGN * (PI_F/64.0f) * (float)l, &s, &c);
    cf w; w.x = c; w.y = s;
    #pragma unroll
    for (int k1 = 0; k1 < 3; ++k1) {
      cf a = uA[k1], b = uB[k1];
      uA[k1] = cadd(a, b);
      uB[k1] = cmul(csub(a, b), w);
    }
  }
  #pragma unroll
  for (int h = 32; h >= 1; h >>= 1) {
    const int j = l & (h - 1);
    float s, c; __sincosf(SIGN * PI_F * (float)j / (float)h, &s, &c);
    cf w; w.x = c; w.y = s;
    const bool up = (l & h) != 0;
    #pragma unroll
    for (int k1 = 0; k1 < 3; ++k1) {
      cf pa = shflxor(uA[k1], h);
      cf pb = shflxor(uB[k1], h);
      cf na = up ? cmul(csub(pa, uA[k1]), w) : cadd(uA[k1], pa);
      cf nb = up ? cmul(csub(pb, uB[k1]), w) : cadd(uB[k1], pb);
      uA[k1] = na; uB[k1] = nb;
    }
  }
}

// ---------------- conv kernels ----------------
// Activations in NHWC bf16: act[b][y][x][c], c=64 contiguous.

__global__ void repack_mid_k(const float* __restrict__ ws_mid, __hip_bfloat16* __restrict__ wrep) {
  const int idx = blockIdx.x * 256 + threadIdx.x;
  if (idx >= 7*9*64*64) return;
  const int ci = idx & 63, co = (idx >> 6) & 63, tap = (idx >> 12) % 9, i = idx / (9*4096);
  wrep[idx] = __float2bfloat16(ws_mid[(((size_t)i*64 + co)*64 + ci)*9 + tap]);
}

__global__ void __launch_bounds__(256) conv_in_k(const float* __restrict__ xin,
                                                 const float* __restrict__ w,
                                                 const float* __restrict__ bias,
                                                 __hip_bfloat16* __restrict__ out) {
  __shared__ float tile[2][340];
  const int tx = threadIdx.x & 31, ty = threadIdx.x >> 5;
  const int x0 = blockIdx.x * 32, y0 = blockIdx.y * 8, b = blockIdx.z;
  for (int e = threadIdx.x; e < 680; e += 256) {
    int ci = e / 340, rr = e % 340;
    int iy = y0 - 1 + rr / 34, ix = x0 - 1 + rr % 34;
    float v = 0.f;
    if (iy >= 0 && iy < HH && ix >= 0 && ix < WW)
      v = xin[(b*2 + ci)*HW + iy*WW + ix];
    tile[ci][rr] = v;
  }
  __syncthreads();
  float acc[64];
  #pragma unroll
  for (int co = 0; co < 64; ++co) acc[co] = bias[co];
  #pragma unroll
  for (int ci = 0; ci < 2; ++ci) {
    float v0 = tile[ci][ty*34+tx],     v1 = tile[ci][ty*34+tx+1],     v2 = tile[ci][ty*34+tx+2];
    float v3 = tile[ci][(ty+1)*34+tx], v4 = tile[ci][(ty+1)*34+tx+1], v5 = tile[ci][(ty+1)*34+tx+2];
    float v6 = tile[ci][(ty+2)*34+tx], v7 = tile[ci][(ty+2)*34+tx+1], v8 = tile[ci][(ty+2)*34+tx+2];
    #pragma unroll
    for (int co = 0; co < 64; ++co) {
      const float* wp = w + co*18 + ci*9;
      float a = acc[co];
      a = fmaf(v0, wp[0], a); a = fmaf(v1, wp[1], a); a = fmaf(v2, wp[2], a);
      a = fmaf(v3, wp[3], a); a = fmaf(v4, wp[4], a); a = fmaf(v5, wp[5], a);
      a = fmaf(v6, wp[6], a); a = fmaf(v7, wp[7], a); a = fmaf(v8, wp[8], a);
      acc[co] = a;
    }
  }
  const size_t obase = ((size_t)(b*HH + y0 + ty)*WW + (x0 + tx))*64;
  #pragma unroll
  for (int s = 0; s < 8; ++s) {
    uint4 u;
    __hip_bfloat16* hp = (__hip_bfloat16*)&u;
    #pragma unroll
    for (int j = 0; j < 8; ++j) hp[j] = __float2bfloat16(acc[s*8 + j]);
    *(uint4*)(out + obase + s*8) = u;
  }
}

// MFMA implicit-GEMM mid conv (round-6 tile: BM=128, 2x4 acc/wave)
__global__ void __launch_bounds__(256) conv_mid_mfma_k(
    const __hip_bfloat16* __restrict__ in,    // NHWC
    const __hip_bfloat16* __restrict__ wrep,  // [9][64][64] bf16
    const float* __restrict__ bias,
    __hip_bfloat16* __restrict__ out, int relu) {
  __shared__ __hip_bfloat16 atile[6*34*72];   // 29376 B, ch padded 64->72
  const int tid = threadIdx.x;
  const int l = tid & 63, wv = tid >> 6;
  const int x0 = blockIdx.x * 32, y0 = blockIdx.y * 4, b = blockIdx.z;

  for (int e = tid; e < 204*8; e += 256) {
    int p = e >> 3, s = e & 7;
    int iy = y0 - 1 + p / 34, ix = x0 - 1 + p % 34;
    uint4 v = make_uint4(0u, 0u, 0u, 0u);
    if (iy >= 0 && iy < HH && ix >= 0 && ix < WW)
      v = *(const uint4*)(in + ((size_t)(b*HH + iy)*WW + ix)*64 + s*8);
    *(uint4*)(&atile[p*72 + s*8]) = v;
  }

  floatx4 acc[2][4];
  #pragma unroll
  for (int mt = 0; mt < 2; ++mt)
    #pragma unroll
    for (int nt = 0; nt < 4; ++nt)
      acc[mt][nt] = (floatx4){0.f, 0.f, 0.f, 0.f};

  const int kseg = l >> 4;
  const int lr = l & 15;

  __syncthreads();

  #pragma unroll 1
  for (int tap = 0; tap < 9; ++tap) {
    const int dy = tap / 3, dx = tap - dy*3;
    const __hip_bfloat16* wt = wrep + tap*4096 + lr*64 + kseg*8;
    short8 bf[4][2];
    #pragma unroll
    for (int nt = 0; nt < 4; ++nt) {
      bf[nt][0] = *(const short8*)(wt + nt*1024);
      bf[nt][1] = *(const short8*)(wt + nt*1024 + 32);
    }
    short8 af[2][2];
    #pragma unroll
    for (int mt = 0; mt < 2; ++mt) {
      const int py = wv + dy;
      const int px = mt*16 + lr + dx;
      const __hip_bfloat16* ap = &atile[(py*34 + px)*72 + kseg*8];
      af[mt][0] = *(const short8*)(ap);
      af[mt][1] = *(const short8*)(ap + 32);
    }
    #pragma unroll
    for (int mt = 0; mt < 2; ++mt)
      #pragma unroll
      for (int nt = 0; nt < 4; ++nt) {
        acc[mt][nt] = __builtin_amdgcn_mfma_f32_16x16x32_bf16(af[mt][0], bf[nt][0], acc[mt][nt], 0, 0, 0);
        acc[mt][nt] = __builtin_amdgcn_mfma_f32_16x16x32_bf16(af[mt][1], bf[nt][1], acc[mt][nt], 0, 0, 0);
      }
  }

  __syncthreads();
  __hip_bfloat16* otile = atile;        // [128 pixels][72 pad]
  #pragma unroll
  for (int mt = 0; mt < 2; ++mt) {
    #pragma unroll
    for (int nt = 0; nt < 4; ++nt) {
      const int ch = nt*16 + lr;
      const float bv = bias[ch];
      #pragma unroll
      for (int rr = 0; rr < 4; ++rr) {
        const int px = mt*16 + kseg*4 + rr;
        float v = acc[mt][nt][rr] + bv;
        if (relu) v = fmaxf(v, 0.f);
        otile[(wv*32 + px)*72 + ch] = __float2bfloat16(v);
      }
    }
  }
  __syncthreads();
  #pragma unroll
  for (int iter = 0; iter < 4; ++iter) {
    const int e = iter*256 + tid;
    const int p = e >> 3, s = e & 7;
    const int row = p >> 5, px = p & 31;
    uint4 v = *(const uint4*)(&otile[p*72 + s*8]);
    *(uint4*)(out + ((size_t)(b*HH + y0 + row)*WW + (x0 + px))*64 + s*8) = v;
  }
}

// conv_out (co=2) + CG init, now LDS-staged (round-6 version over-fetched 1.74GB
// from HBM re-reading the 64ch vector per tap; 552us -> memory-bound on waste).
__global__ void __launch_bounds__(256) conv_out_k(const __hip_bfloat16* __restrict__ in,
                                                  const float* __restrict__ w,
                                                  const float* __restrict__ bias,
                                                  const float* __restrict__ xcur,
                                                  const float* __restrict__ under,
                                                  const float* __restrict__ lam,
                                                  cf* __restrict__ r, cf* __restrict__ p,
                                                  cf* __restrict__ xc, float* __restrict__ scL) {
  __shared__ __hip_bfloat16 atile[340*72];   // 34x10 halo x 64ch (pad 72) = 48960 B
  __shared__ float wl[2*64*9];               // 4608 B
  __shared__ float wsum[4];
  const int tid = threadIdx.x;
  const int tx = tid & 31, ty = tid >> 5;
  const int x0 = blockIdx.x * 32, y0 = blockIdx.y * 8, b = blockIdx.z;

  for (int e = tid; e < 340*8; e += 256) {
    int pp = e >> 3, s = e & 7;
    int iy = y0 - 1 + pp / 34, ix = x0 - 1 + pp % 34;
    uint4 v = make_uint4(0u, 0u, 0u, 0u);
    if (iy >= 0 && iy < HH && ix >= 0 && ix < WW)
      v = *(const uint4*)(in + ((size_t)(b*HH + iy)*WW + ix)*64 + s*8);
    *(uint4*)(&atile[pp*72 + s*8]) = v;
  }
  for (int e = tid; e < 2*64*9; e += 256) wl[e] = w[e];
  __syncthreads();

  float a0 = bias[0], a1 = bias[1];
  #pragma unroll 1
  for (int tap = 0; tap < 9; ++tap) {
    const int dy = tap / 3, dx = tap - dy*3;
    const __hip_bfloat16* ap = &atile[((ty + dy)*34 + tx + dx)*72];
    #pragma unroll
    for (int s = 0; s < 8; ++s) {
      short8 v8 = *(const short8*)(ap + s*8);
      const __hip_bfloat16* hv = (const __hip_bfloat16*)&v8;
      #pragma unroll
      for (int j = 0; j < 8; ++j) {
        const float f = __bfloat162float(hv[j]);
        a0 = fmaf(f, wl[(s*8 + j)*9 + tap], a0);
        a1 = fmaf(f, wl[(64 + s*8 + j)*9 + tap], a1);
      }
    }
  }
  const float lamv = lam[0];
  const int y = y0 + ty, x = x0 + tx;
  const int idx2 = y*WW + x;
  float xv0 = xcur[b*2*HW + idx2],  xv1 = xcur[b*2*HW + HW + idx2];
  float u0  = under[b*2*HW + idx2], u1  = under[b*2*HW + HW + idx2];
  float r0 = u0 + lamv * (xv0 + a0);
  float r1 = u1 + lamv * (xv1 + a1);
  const int cidx = b*HW + idx2;
  cf vv; vv.x = r0; vv.y = r1;
  r[cidx] = vv; p[cidx] = vv;
  cf zz; zz.x = 0.f; zz.y = 0.f; xc[cidx] = zz;
  float partial = r0*r0 + r1*r1;
  for (int off = 32; off; off >>= 1) partial += __shfl_down(partial, off);
  const int l = tid & 63, wvid = tid >> 6;
  if (l == 0) wsum[wvid] = partial;
  __syncthreads();
  if (tid == 0) atomicAdd(&scL[b], wsum[0]+wsum[1]+wsum[2]+wsum[3]);
}

// ---------------- CG / FFT kernels ----------------
// scL (128 floats/layer): rtr[it*4+b] (it 0..9), pAp[40+it*4+b], ApAp[80+it*4+b].
// 3 dispatches/iter. rtr recurrence: rtr_new = a^2*ApAp - rtr (Hermitian A).

__global__ void __launch_bounds__(256) pass_a_k(const cf* __restrict__ rold, cf* __restrict__ rnew,
                                                const cf* __restrict__ pold, cf* __restrict__ pnew,
                                                cf* __restrict__ xc, const cf* __restrict__ Ap,
                                                const cf* __restrict__ csm, cf* __restrict__ t,
                                                float* __restrict__ scL, int it) {
  __shared__ cf rowbuf[4][434];
  const int l = threadIdx.x & 63, wv = threadIdx.x >> 6;
  const int y = blockIdx.x * 4 + wv;
  const int c = blockIdx.y, b = blockIdx.z;
  const int rowoff = b*HW + y*WW;
  cf pv[6];
  if (it == 0) {
    #pragma unroll
    for (int m = 0; m < 6; ++m) pv[m] = pold[rowoff + l + 64*m];
  } else {
    const float rtrp  = scL[(it-1)*4 + b];
    const float pApp  = scL[40 + (it-1)*4 + b];
    const float ApApp = scL[80 + (it-1)*4 + b];
    const float alpha = rtrp / pApp;
    const float rtrn  = alpha*alpha*ApApp - rtrp;
    const float beta  = rtrn / rtrp;
    if (blockIdx.x == 0 && c == 0 && threadIdx.x == 0) scL[it*4 + b] = rtrn;
    #pragma unroll
    for (int m = 0; m < 6; ++m) {
      const int idx = rowoff + l + 64*m;
      cf rv = rold[idx];
      cf av = Ap[idx];
      rv.x -= alpha*av.x; rv.y -= alpha*av.y;
      cf po = pold[idx];
      pv[m].x = rv.x + beta*po.x; pv[m].y = rv.y + beta*po.y;
      if (c == 0) {
        rnew[idx] = rv;
        pnew[idx] = pv[m];
        cf xv = xc[idx]; xv.x += alpha*po.x; xv.y += alpha*po.y; xc[idx] = xv;
      }
    }
  }
  const cf* crow = csm + (b*CC + c)*HW + y*WW;
  cf v[6];
  #pragma unroll
  for (int m = 0; m < 6; ++m) v[m] = cmul(crow[l + 64*m], pv[m]);
  cf uA[3], uB[3];
  fft384_wave<-1>(l, v, uA, uB);
  const int R3 = 3 * brev7(l);
  cf* rb = rowbuf[wv];                  // wave-private
  #pragma unroll
  for (int k1 = 0; k1 < 3; ++k1) { rb[padi(k1 + R3)] = uA[k1]; rb[padi(k1 + R3 + 3)] = uB[k1]; }
  cf* trow = t + (b*CC + c)*HW + y*WW;
  #pragma unroll
  for (int m = 0; m < 6; ++m) trow[l + 64*m] = rb[padi(l + 64*m)];
}

__global__ void __launch_bounds__(256) pass_b_k(cf* __restrict__ t, const float* __restrict__ mask) {
  __shared__ cf tile[431*9];
  const int b = blockIdx.z, c = blockIdx.y, x0 = blockIdx.x * 8;
  cf* base = t + (b*CC + c)*HW;
  for (int e = threadIdx.x; e < 3072; e += 256) {
    int y = e >> 3, xx = e & 7;
    tile[padi(y)*9 + xx] = base[y*WW + x0 + xx];
  }
  __syncthreads();
  const int l = threadIdx.x & 63, wv = threadIdx.x >> 6;
  const int R3 = 3 * brev7(l);
  for (int rep = 0; rep < 2; ++rep) {
    const int xx = wv*2 + rep, x = x0 + xx;
    cf v[6];
    #pragma unroll
    for (int m = 0; m < 6; ++m) v[m] = tile[padi(l + 64*m)*9 + xx];
    cf uA[3], uB[3];
    fft384_wave<-1>(l, v, uA, uB);
    const float* mrow = mask + b*HW + x;
    #pragma unroll
    for (int k1 = 0; k1 < 3; ++k1) {
      float mA = mrow[(k1 + R3)*WW], mB = mrow[(k1 + R3 + 3)*WW];
      uA[k1].x *= mA; uA[k1].y *= mA; uB[k1].x *= mB; uB[k1].y *= mB;
    }
    __syncthreads();
    #pragma unroll
    for (int k1 = 0; k1 < 3; ++k1) { tile[padi(k1 + R3)*9 + xx] = uA[k1]; tile[padi(k1 + R3 + 3)*9 + xx] = uB[k1]; }
    __syncthreads();
    #pragma unroll
    for (int m = 0; m < 6; ++m) v[m] = tile[padi(l + 64*m)*9 + xx];
    fft384_wave<1>(l, v, uA, uB);
    const float s = 1.0f / 384.0f;
    #pragma unroll
    for (int k1 = 0; k1 < 3; ++k1) {
      uA[k1].x *= s; uA[k1].y *= s; uB[k1].x *= s; uB[k1].y *= s;
      tile[padi(k1 + R3)*9 + xx] = uA[k1]; tile[padi(k1 + R3 + 3)*9 + xx] = uB[k1];
    }
    __syncthreads();
  }
  for (int e = threadIdx.x; e < 3072; e += 256) {
    int y = e >> 3, xx = e & 7;
    base[y*WW + x0 + xx] = tile[padi(y)*9 + xx];
  }
}

// pass_c restructured: one y-row per block (grid HH x BB = 1536 blocks), the 8
// coils split 2-per-wave, cross-wave LDS reduce. Full Ap per row -> exact ApAp.
// (round-6 version: 384 blocks with 8-coil serial chain = tail-bound.)
__global__ void __launch_bounds__(256) pass_c_k(const cf* __restrict__ t, const cf* __restrict__ csm,
                                                const cf* __restrict__ p, cf* __restrict__ Ap,
                                                const float* __restrict__ lam,
                                                float* __restrict__ scL, int it) {
  __shared__ cf rowbuf[4][434];
  __shared__ cf redbuf[3][384];
  const int l = threadIdx.x & 63, wv = threadIdx.x >> 6;
  const int y = blockIdx.x, b = blockIdx.y;
  const int R3 = 3 * brev7(l);
  cf* rb = rowbuf[wv];                  // wave-private
  cf acc[6] = {};
  #pragma unroll 1
  for (int ci = 0; ci < 2; ++ci) {
    const int c = wv*2 + ci;
    const cf* trow = t + (b*CC + c)*HW + y*WW;
    cf v[6];
    #pragma unroll
    for (int m = 0; m < 6; ++m) v[m] = trow[l + 64*m];
    cf uA[3], uB[3];
    fft384_wave<1>(l, v, uA, uB);
    #pragma unroll
    for (int k1 = 0; k1 < 3; ++k1) { rb[padi(k1 + R3)] = uA[k1]; rb[padi(k1 + R3 + 3)] = uB[k1]; }
    const cf* crow = csm + (b*CC + c)*HW + y*WW;
    #pragma unroll
    for (int m = 0; m < 6; ++m) {
      cf cs = crow[l + 64*m];
      cf wz = rb[padi(l + 64*m)];
      acc[m].x += cs.x*wz.x + cs.y*wz.y;
      acc[m].y += cs.x*wz.y - cs.y*wz.x;
    }
  }
  if (wv > 0) {
    #pragma unroll
    for (int m = 0; m < 6; ++m) redbuf[wv - 1][l + 64*m] = acc[m];
  }
  __syncthreads();
  if (wv == 0) {
    #pragma unroll
    for (int m = 0; m < 6; ++m) {
      #pragma unroll
      for (int j = 0; j < 3; ++j) {
        cf o = redbuf[j][l + 64*m];
        acc[m].x += o.x; acc[m].y += o.y;
      }
    }
    const float lamv = lam[0];
    const float sc384 = 1.0f / 384.0f;
    const cf* prow = p + b*HW + y*WW;
    cf* aprow = Ap + b*HW + y*WW;
    float partial = 0.f, partial2 = 0.f;
    #pragma unroll
    for (int m = 0; m < 6; ++m) {
      cf pv = prow[l + 64*m];
      cf ap; ap.x = acc[m].x*sc384 + lamv*pv.x; ap.y = acc[m].y*sc384 + lamv*pv.y;
      aprow[l + 64*m] = ap;
      partial  += pv.x*ap.x + pv.y*ap.y;
      partial2 += ap.x*ap.x + ap.y*ap.y;
    }
    #pragma unroll
    for (int off = 32; off; off >>= 1) {
      partial  += __shfl_down(partial, off);
      partial2 += __shfl_down(partial2, off);
    }
    if (l == 0) {
      atomicAdd(&scL[40 + it*4 + b], partial);
      atomicAdd(&scL[80 + it*4 + b], partial2);
    }
  }
}

// final x = xc + alpha9 * p9, planar output
__global__ void __launch_bounds__(256) final_x_k(const cf* __restrict__ xc, const cf* __restrict__ p9,
                                                 const float* __restrict__ scL, float* __restrict__ out) {
  const int idx = blockIdx.x * 256 + threadIdx.x;
  const int b = idx / HW;
  const int rem = idx - b*HW;
  const float alpha = scL[(CGITERS-1)*4 + b] / scL[40 + (CGITERS-1)*4 + b];
  cf xv = xc[idx], pv = p9[idx];
  xv.x += alpha*pv.x; xv.y += alpha*pv.y;
  out[b*2*HW + rem] = xv.x;
  out[b*2*HW + HW + rem] = xv.y;
}

__global__ void zero_sc_k(float* sc) {
  for (int i = threadIdx.x; i < NLAYERS*128; i += 256) sc[i] = 0.f;
}

extern "C" void kernel_launch(void* const* d_in, const int* in_sizes, int n_in,
                              void* d_out, int out_size, void* d_ws, size_t ws_size,
                              hipStream_t stream) {
  (void)in_sizes; (void)n_in; (void)out_size; (void)ws_size;
  const float* under  = (const float*)d_in[0];
  const cf*    csm    = (const cf*)d_in[1];
  const float* mask   = (const float*)d_in[2];
  const float* lam    = (const float*)d_in[3];
  const float* w_in   = (const float*)d_in[4];
  const float* b_in   = (const float*)d_in[5];
  const float* ws_mid = (const float*)d_in[6];
  const float* bs_mid = (const float*)d_in[7];
  const float* w_out  = (const float*)d_in[8];
  const float* b_out  = (const float*)d_in[9];
  float* xcur = (float*)d_out;

  char* bws = (char*)d_ws;
  size_t off = 0;
  auto carve = [&](size_t bytes) { char* pp = bws + off; off += (bytes + 255) & ~(size_t)255; return (void*)pp; };
  __hip_bfloat16* actA = (__hip_bfloat16*)carve((size_t)BB*64*HW*2);
  __hip_bfloat16* actB = (__hip_bfloat16*)carve((size_t)BB*64*HW*2);
  cf* t     = (cf*)carve((size_t)BB*CC*HW*8);
  cf* rbuf0 = (cf*)carve((size_t)BB*HW*8);
  cf* rbuf1 = (cf*)carve((size_t)BB*HW*8);
  cf* pbuf0 = (cf*)carve((size_t)BB*HW*8);
  cf* pbuf1 = (cf*)carve((size_t)BB*HW*8);
  cf* xc    = (cf*)carve((size_t)BB*HW*8);
  cf* Ap    = (cf*)carve((size_t)BB*HW*8);
  float* sc = (float*)carve(4096);
  __hip_bfloat16* wrep = (__hip_bfloat16*)carve((size_t)7*9*64*64*2);

  hipMemcpyAsync(xcur, under, (size_t)BB*2*HW*sizeof(float), hipMemcpyDeviceToDevice, stream);

  zero_sc_k<<<1, 256, 0, stream>>>(sc);
  repack_mid_k<<<(7*9*64*64 + 255)/256, 256, 0, stream>>>(ws_mid, wrep);

  dim3 cgrid(WW/32, HH/8, BB);       // conv_in / conv_out (32x8 tiles)
  dim3 mgrid(WW/32, HH/4, BB);       // conv_mid (32x4 tiles)
  dim3 agrid(HH/4, CC, BB);
  dim3 bgrid(WW/8, CC, BB);
  dim3 c2grid(HH, BB);               // pass_c: one row per block
  const int egrid = BB*HW/256;

  __hip_bfloat16* bufs[2] = { actA, actB };
  cf* rb[2] = { rbuf0, rbuf1 };
  cf* pb[2] = { pbuf0, pbuf1 };

  for (int layer = 0; layer < NLAYERS; ++layer) {
    float* scL = sc + layer*128;
    conv_in_k<<<cgrid, 256, 0, stream>>>(xcur, w_in, b_in, bufs[0]);
    for (int i = 0; i < 7; ++i) {
      conv_mid_mfma_k<<<mgrid, 256, 0, stream>>>(bufs[i & 1], wrep + (size_t)i*9*4096,
                                                 bs_mid + i*64, bufs[(i + 1) & 1], (i % 2 == 0) ? 1 : 0);
    }
    conv_out_k<<<cgrid, 256, 0, stream>>>(bufs[1], w_out, b_out, xcur, under, lam,
                                          rbuf0, pbuf0, xc, scL);
    for (int it = 0; it < CGITERS; ++it) {
      cf* rold = rb[(it + 1) & 1];
      cf* rnew = rb[it & 1];
      cf* pold = pb[(it + 1) & 1];
      cf* pnew = pb[it & 1];
      if (it == 0) { rold = rbuf0; pold = pbuf0; rnew = rbuf0; pnew = pbuf0; }
      pass_a_k<<<agrid, 256, 0, stream>>>(rold, rnew, pold, pnew, xc, Ap, csm, t, scL, it);
      pass_b_k<<<bgrid, 256, 0, stream>>>(t, mask);
      pass_c_k<<<c2grid, 256, 0, stream>>>(t, csm, pnew, Ap, lam, scL, it);
    }
    final_x_k<<<egrid, 256, 0, stream>>>(xc, pb[(CGITERS - 1) & 1], scL, xcur);
  }
}

// Round 8
// 9535.670 us; speedup vs baseline: 3.4621x; 1.1586x over previous
//
#include <hip/hip_runtime.h>
#include <hip/hip_bf16.h>
#include <math.h>

#define HH 384
#define WW 384
#define HW (HH*WW)
#define BB 4
#define CC 8
#define NLAYERS 5
#define CGITERS 10
#define PI_F 3.14159265358979323846f

typedef __attribute__((ext_vector_type(8))) short short8;
typedef __attribute__((ext_vector_type(4))) float floatx4;

struct cf { float x, y; };
__device__ __forceinline__ cf cadd(cf a, cf b){ cf r; r.x=a.x+b.x; r.y=a.y+b.y; return r; }
__device__ __forceinline__ cf csub(cf a, cf b){ cf r; r.x=a.x-b.x; r.y=a.y-b.y; return r; }
__device__ __forceinline__ cf cmul(cf a, cf b){ cf r; r.x=a.x*b.x - a.y*b.y; r.y=a.x*b.y + a.y*b.x; return r; }
__device__ __forceinline__ cf csqr(cf a){ cf r; r.x = a.x*a.x - a.y*a.y; r.y = 2.f*a.x*a.y; return r; }
__device__ __forceinline__ cf shflxor(cf v, int m){ cf r; r.x = __shfl_xor(v.x, m); r.y = __shfl_xor(v.y, m); return r; }
__device__ __forceinline__ int brev7(int l){ return (int)(__brev((unsigned)l) >> 25); }
__device__ __forceinline__ int padi(int i){ return i + (i >> 3); }

__device__ __forceinline__ void radix3(cf a0, cf a1, cf a2, float s3, cf y[3]) {
  float tx = a1.x + a2.x, ty_ = a1.y + a2.y;
  float ux = a1.x - a2.x, uy = a1.y - a2.y;
  y[0].x = a0.x + tx;              y[0].y = a0.y + ty_;
  y[1].x = a0.x - 0.5f*tx - s3*uy; y[1].y = a0.y - 0.5f*ty_ + s3*ux;
  y[2].x = a0.x - 0.5f*tx + s3*uy; y[2].y = a0.y - 0.5f*ty_ - s3*ux;
}

// 384-point DFT across one 64-lane wave. SIGN=-1 fwd, +1 inverse (no 1/N scale).
// ONE sincos; all other twiddles derived: wB1 = wA1*exp(SIGN*i*pi/3),
// stage-64 w = wA1^3, stages h<=32 by successive squaring with the
// up-lane identity w_h = -u_h  =>  upper' = (local - partner) * u_h.
template<int SIGN>
__device__ __forceinline__ void fft384_wave(int l, const cf v[6], cf uA[3], cf uB[3]) {
  const float s3 = SIGN * 0.8660254037844386f;
  radix3(v[0], v[2], v[4], s3, uA);
  radix3(v[1], v[3], v[5], s3, uB);
  float sA, cA;
  __sincosf(SIGN * (2.0f * PI_F / 384.0f) * (float)l, &sA, &cA);
  cf wA1; wA1.x = cA; wA1.y = sA;
  cf wA2 = csqr(wA1);
  cf w6; w6.x = 0.5f; w6.y = s3;            // exp(SIGN*i*pi/3)
  cf wB1 = cmul(wA1, w6);
  cf wB2 = csqr(wB1);
  uA[1] = cmul(uA[1], wA1); uA[2] = cmul(uA[2], wA2);
  uB[1] = cmul(uB[1], wB1); uB[2] = cmul(uB[2], wB2);
  cf u = cmul(wA2, wA1);                    // exp(SIGN*i*pi*l/64): stage h=64 twiddle
  #pragma unroll
  for (int k1 = 0; k1 < 3; ++k1) {
    cf a = uA[k1], b = uB[k1];
    uA[k1] = cadd(a, b);
    uB[k1] = cmul(csub(a, b), u);
  }
  #pragma unroll
  for (int h = 32; h >= 1; h >>= 1) {
    u = csqr(u);                             // exp(SIGN*i*pi*l/h)
    const bool up = (l & h) != 0;
    #pragma unroll
    for (int k1 = 0; k1 < 3; ++k1) {
      cf pa = shflxor(uA[k1], h);
      cf pb = shflxor(uB[k1], h);
      cf na = up ? cmul(csub(uA[k1], pa), u) : cadd(uA[k1], pa);
      cf nb = up ? cmul(csub(uB[k1], pb), u) : cadd(uB[k1], pb);
      uA[k1] = na; uB[k1] = nb;
    }
  }
}

// ---------------- conv kernels ----------------
// Activations in NHWC bf16: act[b][y][x][c], c=64 contiguous.

__global__ void repack_mid_k(const float* __restrict__ ws_mid, __hip_bfloat16* __restrict__ wrep) {
  const int idx = blockIdx.x * 256 + threadIdx.x;
  if (idx >= 7*9*64*64) return;
  const int ci = idx & 63, co = (idx >> 6) & 63, tap = (idx >> 12) % 9, i = idx / (9*4096);
  wrep[idx] = __float2bfloat16(ws_mid[(((size_t)i*64 + co)*64 + ci)*9 + tap]);
}

__global__ void __launch_bounds__(256) conv_in_k(const float* __restrict__ xin,
                                                 const float* __restrict__ w,
                                                 const float* __restrict__ bias,
                                                 __hip_bfloat16* __restrict__ out) {
  __shared__ float tile[2][340];
  const int tx = threadIdx.x & 31, ty = threadIdx.x >> 5;
  const int x0 = blockIdx.x * 32, y0 = blockIdx.y * 8, b = blockIdx.z;
  for (int e = threadIdx.x; e < 680; e += 256) {
    int ci = e / 340, rr = e % 340;
    int iy = y0 - 1 + rr / 34, ix = x0 - 1 + rr % 34;
    float v = 0.f;
    if (iy >= 0 && iy < HH && ix >= 0 && ix < WW)
      v = xin[(b*2 + ci)*HW + iy*WW + ix];
    tile[ci][rr] = v;
  }
  __syncthreads();
  float acc[64];
  #pragma unroll
  for (int co = 0; co < 64; ++co) acc[co] = bias[co];
  #pragma unroll
  for (int ci = 0; ci < 2; ++ci) {
    float v0 = tile[ci][ty*34+tx],     v1 = tile[ci][ty*34+tx+1],     v2 = tile[ci][ty*34+tx+2];
    float v3 = tile[ci][(ty+1)*34+tx], v4 = tile[ci][(ty+1)*34+tx+1], v5 = tile[ci][(ty+1)*34+tx+2];
    float v6 = tile[ci][(ty+2)*34+tx], v7 = tile[ci][(ty+2)*34+tx+1], v8 = tile[ci][(ty+2)*34+tx+2];
    #pragma unroll
    for (int co = 0; co < 64; ++co) {
      const float* wp = w + co*18 + ci*9;
      float a = acc[co];
      a = fmaf(v0, wp[0], a); a = fmaf(v1, wp[1], a); a = fmaf(v2, wp[2], a);
      a = fmaf(v3, wp[3], a); a = fmaf(v4, wp[4], a); a = fmaf(v5, wp[5], a);
      a = fmaf(v6, wp[6], a); a = fmaf(v7, wp[7], a); a = fmaf(v8, wp[8], a);
      acc[co] = a;
    }
  }
  const size_t obase = ((size_t)(b*HH + y0 + ty)*WW + (x0 + tx))*64;
  #pragma unroll
  for (int s = 0; s < 8; ++s) {
    uint4 u;
    __hip_bfloat16* hp = (__hip_bfloat16*)&u;
    #pragma unroll
    for (int j = 0; j < 8; ++j) hp[j] = __float2bfloat16(acc[s*8 + j]);
    *(uint4*)(out + obase + s*8) = u;
  }
}

// MFMA implicit-GEMM mid conv. Mw=64 pixels/wave (256/block): halves per-wave
// B-weight L2 traffic vs Mw=32 (the measured 94k cyc/CU term). B double-buffered
// across taps to hide L2 latency behind the 32-MFMA issue window.
__global__ void __launch_bounds__(256) conv_mid_mfma_k(
    const __hip_bfloat16* __restrict__ in,    // NHWC
    const __hip_bfloat16* __restrict__ wrep,  // [9][64][64] bf16
    const float* __restrict__ bias,
    __hip_bfloat16* __restrict__ out, int relu) {
  __shared__ __hip_bfloat16 atile[10*34*72];  // 48960 B
  const int tid = threadIdx.x;
  const int l = tid & 63, wv = tid >> 6;
  const int x0 = blockIdx.x * 32, y0 = blockIdx.y * 8, b = blockIdx.z;

  for (int e = tid; e < 340*8; e += 256) {
    int p = e >> 3, s = e & 7;
    int iy = y0 - 1 + p / 34, ix = x0 - 1 + p % 34;
    uint4 v = make_uint4(0u, 0u, 0u, 0u);
    if (iy >= 0 && iy < HH && ix >= 0 && ix < WW)
      v = *(const uint4*)(in + ((size_t)(b*HH + iy)*WW + ix)*64 + s*8);
    *(uint4*)(&atile[p*72 + s*8]) = v;
  }

  floatx4 acc[4][4];
  #pragma unroll
  for (int mt = 0; mt < 4; ++mt)
    #pragma unroll
    for (int nt = 0; nt < 4; ++nt)
      acc[mt][nt] = (floatx4){0.f, 0.f, 0.f, 0.f};

  const int kseg = l >> 4;
  const int lr = l & 15;

  // prefetch tap 0 weights while atile staging is in flight
  const __hip_bfloat16* wlane = wrep + lr*64 + kseg*8;
  short8 bf[4][2];
  #pragma unroll
  for (int nt = 0; nt < 4; ++nt) {
    bf[nt][0] = *(const short8*)(wlane + nt*1024);
    bf[nt][1] = *(const short8*)(wlane + nt*1024 + 32);
  }

  __syncthreads();

  #pragma unroll 1
  for (int tap = 0; tap < 9; ++tap) {
    short8 bfn[4][2];
    if (tap < 8) {
      const __hip_bfloat16* wn = wlane + (tap + 1)*4096;
      #pragma unroll
      for (int nt = 0; nt < 4; ++nt) {
        bfn[nt][0] = *(const short8*)(wn + nt*1024);
        bfn[nt][1] = *(const short8*)(wn + nt*1024 + 32);
      }
    }
    const int dy = tap / 3, dx = tap - dy*3;
    short8 af[4][2];
    #pragma unroll
    for (int mt = 0; mt < 4; ++mt) {
      const int ry = 2*wv + (mt >> 1) + dy;
      const int px = (mt & 1)*16 + lr + dx;
      const __hip_bfloat16* ap = &atile[(ry*34 + px)*72 + kseg*8];
      af[mt][0] = *(const short8*)(ap);
      af[mt][1] = *(const short8*)(ap + 32);
    }
    #pragma unroll
    for (int mt = 0; mt < 4; ++mt)
      #pragma unroll
      for (int nt = 0; nt < 4; ++nt) {
        acc[mt][nt] = __builtin_amdgcn_mfma_f32_16x16x32_bf16(af[mt][0], bf[nt][0], acc[mt][nt], 0, 0, 0);
        acc[mt][nt] = __builtin_amdgcn_mfma_f32_16x16x32_bf16(af[mt][1], bf[nt][1], acc[mt][nt], 0, 0, 0);
      }
    if (tap < 8) {
      #pragma unroll
      for (int nt = 0; nt < 4; ++nt) { bf[nt][0] = bfn[nt][0]; bf[nt][1] = bfn[nt][1]; }
    }
  }

  // LDS-transpose epilogue -> coalesced 16B stores
  __syncthreads();
  __hip_bfloat16* otile = atile;        // [256 pixels][72 pad]
  #pragma unroll
  for (int mt = 0; mt < 4; ++mt) {
    const int row = 2*wv + (mt >> 1);
    #pragma unroll
    for (int nt = 0; nt < 4; ++nt) {
      const int ch = nt*16 + lr;
      const float bv = bias[ch];
      #pragma unroll
      for (int rr = 0; rr < 4; ++rr) {
        const int px = (mt & 1)*16 + kseg*4 + rr;
        float v = acc[mt][nt][rr] + bv;
        if (relu) v = fmaxf(v, 0.f);
        otile[(row*32 + px)*72 + ch] = __float2bfloat16(v);
      }
    }
  }
  __syncthreads();
  #pragma unroll
  for (int iter = 0; iter < 8; ++iter) {
    const int p = iter*32 + (tid >> 3), s = tid & 7;
    const int row = p >> 5, px = p & 31;
    uint4 v = *(const uint4*)(&otile[p*72 + s*8]);
    *(uint4*)(out + ((size_t)(b*HH + y0 + row)*WW + (x0 + px))*64 + s*8) = v;
  }
}

// conv_out (co=2) + CG init, LDS-staged
__global__ void __launch_bounds__(256) conv_out_k(const __hip_bfloat16* __restrict__ in,
                                                  const float* __restrict__ w,
                                                  const float* __restrict__ bias,
                                                  const float* __restrict__ xcur,
                                                  const float* __restrict__ under,
                                                  const float* __restrict__ lam,
                                                  cf* __restrict__ r, cf* __restrict__ p,
                                                  cf* __restrict__ xc, float* __restrict__ scL) {
  __shared__ __hip_bfloat16 atile[340*72];
  __shared__ float wl[2*64*9];
  __shared__ float wsum[4];
  const int tid = threadIdx.x;
  const int tx = tid & 31, ty = tid >> 5;
  const int x0 = blockIdx.x * 32, y0 = blockIdx.y * 8, b = blockIdx.z;

  for (int e = tid; e < 340*8; e += 256) {
    int pp = e >> 3, s = e & 7;
    int iy = y0 - 1 + pp / 34, ix = x0 - 1 + pp % 34;
    uint4 v = make_uint4(0u, 0u, 0u, 0u);
    if (iy >= 0 && iy < HH && ix >= 0 && ix < WW)
      v = *(const uint4*)(in + ((size_t)(b*HH + iy)*WW + ix)*64 + s*8);
    *(uint4*)(&atile[pp*72 + s*8]) = v;
  }
  for (int e = tid; e < 2*64*9; e += 256) wl[e] = w[e];
  __syncthreads();

  float a0 = bias[0], a1 = bias[1];
  #pragma unroll 1
  for (int tap = 0; tap < 9; ++tap) {
    const int dy = tap / 3, dx = tap - dy*3;
    const __hip_bfloat16* ap = &atile[((ty + dy)*34 + tx + dx)*72];
    #pragma unroll
    for (int s = 0; s < 8; ++s) {
      short8 v8 = *(const short8*)(ap + s*8);
      const __hip_bfloat16* hv = (const __hip_bfloat16*)&v8;
      #pragma unroll
      for (int j = 0; j < 8; ++j) {
        const float f = __bfloat162float(hv[j]);
        a0 = fmaf(f, wl[(s*8 + j)*9 + tap], a0);
        a1 = fmaf(f, wl[(64 + s*8 + j)*9 + tap], a1);
      }
    }
  }
  const float lamv = lam[0];
  const int y = y0 + ty, x = x0 + tx;
  const int idx2 = y*WW + x;
  float xv0 = xcur[b*2*HW + idx2],  xv1 = xcur[b*2*HW + HW + idx2];
  float u0  = under[b*2*HW + idx2], u1  = under[b*2*HW + HW + idx2];
  float r0 = u0 + lamv * (xv0 + a0);
  float r1 = u1 + lamv * (xv1 + a1);
  const int cidx = b*HW + idx2;
  cf vv; vv.x = r0; vv.y = r1;
  r[cidx] = vv; p[cidx] = vv;
  cf zz; zz.x = 0.f; zz.y = 0.f; xc[cidx] = zz;
  float partial = r0*r0 + r1*r1;
  for (int off = 32; off; off >>= 1) partial += __shfl_down(partial, off);
  const int l = tid & 63, wvid = tid >> 6;
  if (l == 0) wsum[wvid] = partial;
  __syncthreads();
  if (tid == 0) atomicAdd(&scL[b], wsum[0]+wsum[1]+wsum[2]+wsum[3]);
}

// ---------------- CG / FFT kernels ----------------
// scL (128 floats/layer): rtr[it*4+b] (it 0..9), pAp[40+it*4+b], ApAp[80+it*4+b].
// 3 dispatches/iter. rtr recurrence: rtr_new = a^2*ApAp - rtr (Hermitian A).

__global__ void __launch_bounds__(256) pass_a_k(const cf* __restrict__ rold, cf* __restrict__ rnew,
                                                const cf* __restrict__ pold, cf* __restrict__ pnew,
                                                cf* __restrict__ xc, const cf* __restrict__ Ap,
                                                const cf* __restrict__ csm, cf* __restrict__ t,
                                                float* __restrict__ scL, int it) {
  __shared__ cf rowbuf[4][434];
  const int l = threadIdx.x & 63, wv = threadIdx.x >> 6;
  const int y = blockIdx.x * 4 + wv;
  const int c = blockIdx.y, b = blockIdx.z;
  const int rowoff = b*HW + y*WW;
  cf pv[6];
  if (it == 0) {
    #pragma unroll
    for (int m = 0; m < 6; ++m) pv[m] = pold[rowoff + l + 64*m];
  } else {
    const float rtrp  = scL[(it-1)*4 + b];
    const float pApp  = scL[40 + (it-1)*4 + b];
    const float ApApp = scL[80 + (it-1)*4 + b];
    const float alpha = rtrp / pApp;
    const float rtrn  = alpha*alpha*ApApp - rtrp;
    const float beta  = rtrn / rtrp;
    if (blockIdx.x == 0 && c == 0 && threadIdx.x == 0) scL[it*4 + b] = rtrn;
    #pragma unroll
    for (int m = 0; m < 6; ++m) {
      const int idx = rowoff + l + 64*m;
      cf rv = rold[idx];
      cf av = Ap[idx];
      rv.x -= alpha*av.x; rv.y -= alpha*av.y;
      cf po = pold[idx];
      pv[m].x = rv.x + beta*po.x; pv[m].y = rv.y + beta*po.y;
      if (c == 0) {
        rnew[idx] = rv;
        pnew[idx] = pv[m];
        cf xv = xc[idx]; xv.x += alpha*po.x; xv.y += alpha*po.y; xc[idx] = xv;
      }
    }
  }
  const cf* crow = csm + (b*CC + c)*HW + y*WW;
  cf v[6];
  #pragma unroll
  for (int m = 0; m < 6; ++m) v[m] = cmul(crow[l + 64*m], pv[m]);
  cf uA[3], uB[3];
  fft384_wave<-1>(l, v, uA, uB);
  const int R3 = 3 * brev7(l);
  cf* rb = rowbuf[wv];                  // wave-private
  #pragma unroll
  for (int k1 = 0; k1 < 3; ++k1) { rb[padi(k1 + R3)] = uA[k1]; rb[padi(k1 + R3 + 3)] = uB[k1]; }
  cf* trow = t + (b*CC + c)*HW + y*WW;
  #pragma unroll
  for (int m = 0; m < 6; ++m) trow[l + 64*m] = rb[padi(l + 64*m)];
}

__global__ void __launch_bounds__(256) pass_b_k(cf* __restrict__ t, const float* __restrict__ mask) {
  __shared__ cf tile[431*9];
  const int b = blockIdx.z, c = blockIdx.y, x0 = blockIdx.x * 8;
  cf* base = t + (b*CC + c)*HW;
  for (int e = threadIdx.x; e < 3072; e += 256) {
    int y = e >> 3, xx = e & 7;
    tile[padi(y)*9 + xx] = base[y*WW + x0 + xx];
  }
  __syncthreads();
  const int l = threadIdx.x & 63, wv = threadIdx.x >> 6;
  const int R3 = 3 * brev7(l);
  for (int rep = 0; rep < 2; ++rep) {
    const int xx = wv*2 + rep, x = x0 + xx;
    cf v[6];
    #pragma unroll
    for (int m = 0; m < 6; ++m) v[m] = tile[padi(l + 64*m)*9 + xx];
    cf uA[3], uB[3];
    fft384_wave<-1>(l, v, uA, uB);
    const float* mrow = mask + b*HW + x;
    #pragma unroll
    for (int k1 = 0; k1 < 3; ++k1) {
      float mA = mrow[(k1 + R3)*WW], mB = mrow[(k1 + R3 + 3)*WW];
      uA[k1].x *= mA; uA[k1].y *= mA; uB[k1].x *= mB; uB[k1].y *= mB;
    }
    __syncthreads();
    #pragma unroll
    for (int k1 = 0; k1 < 3; ++k1) { tile[padi(k1 + R3)*9 + xx] = uA[k1]; tile[padi(k1 + R3 + 3)*9 + xx] = uB[k1]; }
    __syncthreads();
    #pragma unroll
    for (int m = 0; m < 6; ++m) v[m] = tile[padi(l + 64*m)*9 + xx];
    fft384_wave<1>(l, v, uA, uB);
    const float s = 1.0f / 384.0f;
    #pragma unroll
    for (int k1 = 0; k1 < 3; ++k1) {
      uA[k1].x *= s; uA[k1].y *= s; uB[k1].x *= s; uB[k1].y *= s;
      tile[padi(k1 + R3)*9 + xx] = uA[k1]; tile[padi(k1 + R3 + 3)*9 + xx] = uB[k1];
    }
    __syncthreads();
  }
  for (int e = threadIdx.x; e < 3072; e += 256) {
    int y = e >> 3, xx = e & 7;
    base[y*WW + x0 + xx] = tile[padi(y)*9 + xx];
  }
}

// pass_c: one y-row per block (HH x BB grid), 8 coils split 2/wave, LDS reduce.
__global__ void __launch_bounds__(256) pass_c_k(const cf* __restrict__ t, const cf* __restrict__ csm,
                                                const cf* __restrict__ p, cf* __restrict__ Ap,
                                                const float* __restrict__ lam,
                                                float* __restrict__ scL, int it) {
  __shared__ cf rowbuf[4][434];
  __shared__ cf redbuf[3][384];
  const int l = threadIdx.x & 63, wv = threadIdx.x >> 6;
  const int y = blockIdx.x, b = blockIdx.y;
  const int R3 = 3 * brev7(l);
  cf* rb = rowbuf[wv];                  // wave-private
  cf acc[6] = {};
  #pragma unroll 1
  for (int ci = 0; ci < 2; ++ci) {
    const int c = wv*2 + ci;
    const cf* trow = t + (b*CC + c)*HW + y*WW;
    cf v[6];
    #pragma unroll
    for (int m = 0; m < 6; ++m) v[m] = trow[l + 64*m];
    cf uA[3], uB[3];
    fft384_wave<1>(l, v, uA, uB);
    #pragma unroll
    for (int k1 = 0; k1 < 3; ++k1) { rb[padi(k1 + R3)] = uA[k1]; rb[padi(k1 + R3 + 3)] = uB[k1]; }
    const cf* crow = csm + (b*CC + c)*HW + y*WW;
    #pragma unroll
    for (int m = 0; m < 6; ++m) {
      cf cs = crow[l + 64*m];
      cf wz = rb[padi(l + 64*m)];
      acc[m].x += cs.x*wz.x + cs.y*wz.y;
      acc[m].y += cs.x*wz.y - cs.y*wz.x;
    }
  }
  if (wv > 0) {
    #pragma unroll
    for (int m = 0; m < 6; ++m) redbuf[wv - 1][l + 64*m] = acc[m];
  }
  __syncthreads();
  if (wv == 0) {
    #pragma unroll
    for (int m = 0; m < 6; ++m) {
      #pragma unroll
      for (int j = 0; j < 3; ++j) {
        cf o = redbuf[j][l + 64*m];
        acc[m].x += o.x; acc[m].y += o.y;
      }
    }
    const float lamv = lam[0];
    const float sc384 = 1.0f / 384.0f;
    const cf* prow = p + b*HW + y*WW;
    cf* aprow = Ap + b*HW + y*WW;
    float partial = 0.f, partial2 = 0.f;
    #pragma unroll
    for (int m = 0; m < 6; ++m) {
      cf pv = prow[l + 64*m];
      cf ap; ap.x = acc[m].x*sc384 + lamv*pv.x; ap.y = acc[m].y*sc384 + lamv*pv.y;
      aprow[l + 64*m] = ap;
      partial  += pv.x*ap.x + pv.y*ap.y;
      partial2 += ap.x*ap.x + ap.y*ap.y;
    }
    #pragma unroll
    for (int off = 32; off; off >>= 1) {
      partial  += __shfl_down(partial, off);
      partial2 += __shfl_down(partial2, off);
    }
    if (l == 0) {
      atomicAdd(&scL[40 + it*4 + b], partial);
      atomicAdd(&scL[80 + it*4 + b], partial2);
    }
  }
}

// final x = xc + alpha9 * p9, planar output
__global__ void __launch_bounds__(256) final_x_k(const cf* __restrict__ xc, const cf* __restrict__ p9,
                                                 const float* __restrict__ scL, float* __restrict__ out) {
  const int idx = blockIdx.x * 256 + threadIdx.x;
  const int b = idx / HW;
  const int rem = idx - b*HW;
  const float alpha = scL[(CGITERS-1)*4 + b] / scL[40 + (CGITERS-1)*4 + b];
  cf xv = xc[idx], pv = p9[idx];
  xv.x += alpha*pv.x; xv.y += alpha*pv.y;
  out[b*2*HW + rem] = xv.x;
  out[b*2*HW + HW + rem] = xv.y;
}

__global__ void zero_sc_k(float* sc) {
  for (int i = threadIdx.x; i < NLAYERS*128; i += 256) sc[i] = 0.f;
}

extern "C" void kernel_launch(void* const* d_in, const int* in_sizes, int n_in,
                              void* d_out, int out_size, void* d_ws, size_t ws_size,
                              hipStream_t stream) {
  (void)in_sizes; (void)n_in; (void)out_size; (void)ws_size;
  const float* under  = (const float*)d_in[0];
  const cf*    csm    = (const cf*)d_in[1];
  const float* mask   = (const float*)d_in[2];
  const float* lam    = (const float*)d_in[3];
  const float* w_in   = (const float*)d_in[4];
  const float* b_in   = (const float*)d_in[5];
  const float* ws_mid = (const float*)d_in[6];
  const float* bs_mid = (const float*)d_in[7];
  const float* w_out  = (const float*)d_in[8];
  const float* b_out  = (const float*)d_in[9];
  float* xcur = (float*)d_out;

  char* bws = (char*)d_ws;
  size_t off = 0;
  auto carve = [&](size_t bytes) { char* pp = bws + off; off += (bytes + 255) & ~(size_t)255; return (void*)pp; };
  __hip_bfloat16* actA = (__hip_bfloat16*)carve((size_t)BB*64*HW*2);
  __hip_bfloat16* actB = (__hip_bfloat16*)carve((size_t)BB*64*HW*2);
  cf* t     = (cf*)carve((size_t)BB*CC*HW*8);
  cf* rbuf0 = (cf*)carve((size_t)BB*HW*8);
  cf* rbuf1 = (cf*)carve((size_t)BB*HW*8);
  cf* pbuf0 = (cf*)carve((size_t)BB*HW*8);
  cf* pbuf1 = (cf*)carve((size_t)BB*HW*8);
  cf* xc    = (cf*)carve((size_t)BB*HW*8);
  cf* Ap    = (cf*)carve((size_t)BB*HW*8);
  float* sc = (float*)carve(4096);
  __hip_bfloat16* wrep = (__hip_bfloat16*)carve((size_t)7*9*64*64*2);

  hipMemcpyAsync(xcur, under, (size_t)BB*2*HW*sizeof(float), hipMemcpyDeviceToDevice, stream);

  zero_sc_k<<<1, 256, 0, stream>>>(sc);
  repack_mid_k<<<(7*9*64*64 + 255)/256, 256, 0, stream>>>(ws_mid, wrep);

  dim3 cgrid(WW/32, HH/8, BB);       // conv_in / conv_mid / conv_out (32x8 tiles)
  dim3 agrid(HH/4, CC, BB);
  dim3 bgrid(WW/8, CC, BB);
  dim3 c2grid(HH, BB);               // pass_c: one row per block
  const int egrid = BB*HW/256;

  __hip_bfloat16* bufs[2] = { actA, actB };
  cf* rb[2] = { rbuf0, rbuf1 };
  cf* pb[2] = { pbuf0, pbuf1 };

  for (int layer = 0; layer < NLAYERS; ++layer) {
    float* scL = sc + layer*128;
    conv_in_k<<<cgrid, 256, 0, stream>>>(xcur, w_in, b_in, bufs[0]);
    for (int i = 0; i < 7; ++i) {
      conv_mid_mfma_k<<<cgrid, 256, 0, stream>>>(bufs[i & 1], wrep + (size_t)i*9*4096,
                                                 bs_mid + i*64, bufs[(i + 1) & 1], (i % 2 == 0) ? 1 : 0);
    }
    conv_out_k<<<cgrid, 256, 0, stream>>>(bufs[1], w_out, b_out, xcur, under, lam,
                                          rbuf0, pbuf0, xc, scL);
    for (int it = 0; it < CGITERS; ++it) {
      cf* rold = rb[(it + 1) & 1];
      cf* rnew = rb[it & 1];
      cf* pold = pb[(it + 1) & 1];
      cf* pnew = pb[it & 1];
      if (it == 0) { rold = rbuf0; pold = pbuf0; rnew = rbuf0; pnew = pbuf0; }
      pass_a_k<<<agrid, 256, 0, stream>>>(rold, rnew, pold, pnew, xc, Ap, csm, t, scL, it);
      pass_b_k<<<bgrid, 256, 0, stream>>>(t, mask);
      pass_c_k<<<c2grid, 256, 0, stream>>>(t, csm, pnew, Ap, lam, scL, it);
    }
    final_x_k<<<egrid, 256, 0, stream>>>(xc, pb[(CGITERS - 1) & 1], scL, xcur);
  }
}